// Round 1
// baseline (6665.326 us; speedup 1.0000x reference)
//
#include <hip/hip_runtime.h>
#include <hip/hip_bf16.h>

// Problem constants
#define B_  8
#define D_  256
#define M_  2048
#define DT_ 64
#define KT_ 16
#define UP_ 4
#define NPT (B_ * M_)   // 16384 total points

// ---------------------------------------------------------------------------
// Generic tiled fp32 GEMM:  Y = [relu](W(OC,IC) @ X(IC,N) + bias)  [+= existing Y]
// XM: 0 = "CM"  X[c,n] = Xsrc[(b*ld + c)*2048 + m]   (channel-major per batch)
//     1 = "PM"  X[c,n] = Xsrc[n*ld + c]              (point-major)
// Split inputs: c < split -> X0, else X1 (c-split).
// YM: 0 = CM (B,OC,2048)   1 = PM (N,OC)   2 = OUT (B,256,8192) at col out_off
// ---------------------------------------------------------------------------
template<int XM, int YM, bool RELU, bool ADDY>
__global__ __launch_bounds__(256)
void gemm_k(const float* __restrict__ W, const float* __restrict__ Bv,
            const float* __restrict__ X0, const float* __restrict__ X1,
            float* __restrict__ Y,
            int OC, int IC, int split, int ld0, int ld1, int out_off)
{
  __shared__ float sWt[16][68];  // transposed W tile [kk][o], padded
  __shared__ float sX[16][68];   // X tile [kk][nn], padded
  const int t  = threadIdx.x;
  const int n0 = blockIdx.x * 64;
  const int o0 = blockIdx.y * 64;
  const int b  = n0 >> 11;       // M=2048 per batch, tiles never cross b
  const int m0 = n0 & 2047;
  const int oi = (t >> 4) << 2;  // 0..60
  const int ni = (t & 15) << 2;  // 0..60
  float acc[4][4] = {{0.f}};

  for (int k0 = 0; k0 < IC; k0 += 16) {
    // load W tile (rows are 16-float multiples for all ICs used: 512/256/64)
    {
      int o = t >> 2, kk = (t & 3) << 2;
      const float4 wv = *reinterpret_cast<const float4*>(W + (size_t)(o0 + o) * IC + k0 + kk);
      sWt[kk + 0][o] = wv.x; sWt[kk + 1][o] = wv.y;
      sWt[kk + 2][o] = wv.z; sWt[kk + 3][o] = wv.w;
    }
    // load X tile, coalesced over nn for CM
    #pragma unroll
    for (int r = 0; r < 4; ++r) {
      int kk = (t >> 6) + r * 4;
      int nn = t & 63;
      int c  = k0 + kk;
      float v;
      if (XM == 0) {
        const float* Xp = (c < split) ? (X0 + ((size_t)b * ld0 + c) * 2048)
                                      : (X1 + ((size_t)b * ld1 + (c - split)) * 2048);
        v = Xp[m0 + nn];
      } else {
        int nidx = n0 + nn;
        v = (c < split) ? X0[(size_t)nidx * ld0 + c]
                        : X1[(size_t)nidx * ld1 + (c - split)];
      }
      sX[kk][nn] = v;
    }
    __syncthreads();
    #pragma unroll
    for (int kk = 0; kk < 16; ++kk) {
      float4 wv = *reinterpret_cast<const float4*>(&sWt[kk][oi]);
      float4 xv = *reinterpret_cast<const float4*>(&sX[kk][ni]);
      float w[4] = {wv.x, wv.y, wv.z, wv.w};
      float x[4] = {xv.x, xv.y, xv.z, xv.w};
      #pragma unroll
      for (int i2 = 0; i2 < 4; ++i2)
        #pragma unroll
        for (int j = 0; j < 4; ++j)
          acc[i2][j] = fmaf(w[i2], x[j], acc[i2][j]);
    }
    __syncthreads();
  }

  #pragma unroll
  for (int i2 = 0; i2 < 4; ++i2) {
    int o = o0 + oi + i2;
    float bias = Bv[o];
    #pragma unroll
    for (int j = 0; j < 4; ++j) {
      int nn = ni + j;
      float v = acc[i2][j] + bias;
      if (RELU) v = fmaxf(v, 0.f);
      size_t idx;
      if (YM == 0)      idx = ((size_t)b * OC + o) * 2048 + (m0 + nn);
      else if (YM == 1) idx = (size_t)(n0 + nn) * OC + o;
      else              idx = ((size_t)b * 256 + o) * 8192 + out_off + (m0 + nn);
      if (ADDY) Y[idx] += v; else Y[idx] = v;
    }
  }
}

// ---------------------------------------------------------------------------
// KNN: per batch, stage xyz + sq-norms in LDS; one wave per query point.
// Each lane holds 32 candidate distances; 16 iterative min-extractions with
// top_k-compatible tie-break (lower index wins on equal distance).
// grid = B * (M/16) = 1024 blocks, 256 threads (4 waves x 4 queries each)
// ---------------------------------------------------------------------------
__global__ __launch_bounds__(256)
void knn_k(const float* __restrict__ xyz, int* __restrict__ ids)
{
  __shared__ float sx[2048], sy[2048], sz[2048], ss[2048];
  const int blk = blockIdx.x;
  const int b   = blk >> 7;      // /128
  const int mg  = blk & 127;
  const int t   = threadIdx.x;
  const float* xb = xyz + (size_t)b * 2048 * 3;
  for (int i = t; i < 2048; i += 256) {
    float x = xb[3 * i], y = xb[3 * i + 1], z = xb[3 * i + 2];
    sx[i] = x; sy[i] = y; sz[i] = z;
    ss[i] = x * x + y * y + z * z;
  }
  __syncthreads();
  const int wave = t >> 6, lane = t & 63;
  for (int qi = 0; qi < 4; ++qi) {
    const int m = mg * 16 + wave * 4 + qi;
    const float xm = sx[m], ym = sy[m], zm = sz[m], sqm = ss[m];
    float d[32];
    #pragma unroll
    for (int j = 0; j < 32; ++j) {
      int nn = lane + 64 * j;
      d[j] = sqm + ss[nn] - 2.f * (sx[nn] * xm + sy[nn] * ym + sz[nn] * zm);
    }
    int* outp = ids + ((size_t)b * 2048 + m) * 16;
    for (int it = 0; it < 16; ++it) {
      float bd = 3.4e38f; int bn = 0x7fffffff;
      #pragma unroll
      for (int j = 0; j < 32; ++j) {
        int nn = lane + 64 * j;
        if (d[j] < bd) { bd = d[j]; bn = nn; }
      }
      #pragma unroll
      for (int off = 32; off > 0; off >>= 1) {
        float od = __shfl_xor(bd, off, 64);
        int   on = __shfl_xor(bn, off, 64);
        if (od < bd || (od == bd && on < bn)) { bd = od; bn = on; }
      }
      if ((bn & 63) == lane) {
        #pragma unroll
        for (int j = 0; j < 32; ++j) if (j == (bn >> 6)) d[j] = 3.4e38f;
      }
      if (lane == 0) outp[it] = bn;
    }
  }
}

// ---------------------------------------------------------------------------
// Fused per-point attention: pos-MLP, gather, 4x (wa1+relu+wa2, softmax, pool)
// one block (256 thr) per point; writes f_buf (UP, NPT, 64)
// ---------------------------------------------------------------------------
__global__ __launch_bounds__(256)
void attn_k(const float* __restrict__ q_t, const float* __restrict__ k_t,
            const float* __restrict__ v_t, const int* __restrict__ idsp,
            const float* __restrict__ xyz,
            const float* __restrict__ wp1, const float* __restrict__ bp1,
            const float* __restrict__ wp2, const float* __restrict__ bp2,
            const float* __restrict__ wa1, const float* __restrict__ ba1,
            const float* __restrict__ wa2, const float* __restrict__ ba2,
            float* __restrict__ fb)
{
  const int n = blockIdx.x;          // global point id
  const int b = n >> 11;
  const int t = threadIdx.x;
  __shared__ float s_t1[64][17], s_pos[64][17], s_a0[64][17], s_vp[64][17], s_sm[64][17];
  __shared__ float s_h[256][17];
  __shared__ int   s_id[16];
  __shared__ float s_pr[3][16];

  if (t < 16) s_id[t] = idsp[(size_t)n * 16 + t];
  __syncthreads();
  if (t < 48) {
    int k = t & 15, c = t >> 4;  // c < 3
    s_pr[c][k] = xyz[((size_t)b * 2048 + s_id[k]) * 3 + c] - xyz[(size_t)n * 3 + c];
  }
  __syncthreads();
  // pos layer 1: t1[dt][k] = relu(wp1 @ pr + bp1)
  #pragma unroll
  for (int r = 0; r < 4; ++r) {
    int idx = r * 256 + t, dt = idx >> 4, k = idx & 15;
    float v = wp1[dt * 3] * s_pr[0][k] + wp1[dt * 3 + 1] * s_pr[1][k]
            + wp1[dt * 3 + 2] * s_pr[2][k] + bp1[dt];
    s_t1[dt][k] = fmaxf(v, 0.f);
  }
  __syncthreads();
  // pos layer 2
  #pragma unroll
  for (int r = 0; r < 4; ++r) {
    int idx = r * 256 + t, o = idx >> 4, k = idx & 15;
    float acc = bp2[o];
    for (int c = 0; c < 64; ++c) acc = fmaf(wp2[o * 64 + c], s_t1[c][k], acc);
    s_pos[o][k] = acc;
  }
  __syncthreads();
  // a0 = q - k_nbr + pos ; vp = v_nbr + pos   (coalesced over c)
  #pragma unroll
  for (int r = 0; r < 4; ++r) {
    int idx = r * 256 + t, c = idx & 63, k = idx >> 6;
    float p  = s_pos[c][k];
    float qv = q_t[(size_t)n * 64 + c];
    float kv = k_t[((size_t)b * 2048 + s_id[k]) * 64 + c];
    float vv = v_t[((size_t)b * 2048 + s_id[k]) * 64 + c];
    s_a0[c][k] = qv - kv + p;
    s_vp[c][k] = vv + p;
  }
  __syncthreads();

  for (int i = 0; i < UP_; ++i) {
    const float* W1 = wa1 + (size_t)i * 256 * 64;
    const float* B1 = ba1 + i * 256;
    const float* W2 = wa2 + (size_t)i * 64 * 256;
    const float* B2 = ba2 + i * 64;
    // h = relu(W1 @ a0 + B1)   (256 x 16)
    #pragma unroll
    for (int r = 0; r < 16; ++r) {
      int idx = r * 256 + t, o = idx >> 4, k = idx & 15;
      float acc = B1[o];
      for (int c = 0; c < 64; ++c) acc = fmaf(W1[o * 64 + c], s_a0[c][k], acc);
      s_h[o][k] = fmaxf(acc, 0.f);
    }
    __syncthreads();
    // a2 = (W2 @ h + B2) * scale  (64 x 16)
    #pragma unroll
    for (int r = 0; r < 4; ++r) {
      int idx = r * 256 + t, dt = idx >> 4, k = idx & 15;
      float acc = B2[dt];
      for (int o = 0; o < 256; ++o) acc = fmaf(W2[dt * 256 + o], s_h[o][k], acc);
      s_sm[dt][k] = acc * 0.125f;
    }
    __syncthreads();
    // softmax over k per row
    if (t < 64) {
      float mx = -3.4e38f;
      for (int k = 0; k < 16; ++k) mx = fmaxf(mx, s_sm[t][k]);
      float sum = 0.f;
      for (int k = 0; k < 16; ++k) { float e = __expf(s_sm[t][k] - mx); s_sm[t][k] = e; sum += e; }
      float inv = 1.f / sum;
      for (int k = 0; k < 16; ++k) s_sm[t][k] *= inv;
    }
    __syncthreads();
    // f = sum_k sm * vp
    if (t < 64) {
      float acc = 0.f;
      for (int k = 0; k < 16; ++k) acc = fmaf(s_sm[t][k], s_vp[t][k], acc);
      fb[((size_t)i * NPT + n) * 64 + t] = acc;
    }
    __syncthreads();
  }
}

// ---------------------------------------------------------------------------
extern "C" void kernel_launch(void* const* d_in, const int* in_sizes, int n_in,
                              void* d_out, int out_size, void* d_ws, size_t ws_size,
                              hipStream_t stream)
{
  const float* fq   = (const float*)d_in[0];
  const float* fk   = (const float*)d_in[1];
  const float* xyz  = (const float*)d_in[2];
  const float* w1   = (const float*)d_in[3];
  const float* b1   = (const float*)d_in[4];
  const float* w2   = (const float*)d_in[5];
  const float* b2   = (const float*)d_in[6];
  const float* wres = (const float*)d_in[7];
  const float* bres = (const float*)d_in[8];
  const float* wq   = (const float*)d_in[9];
  const float* bq   = (const float*)d_in[10];
  const float* wk   = (const float*)d_in[11];
  const float* bk   = (const float*)d_in[12];
  const float* wv   = (const float*)d_in[13];
  const float* bv   = (const float*)d_in[14];
  const float* wp1  = (const float*)d_in[15];
  const float* bp1  = (const float*)d_in[16];
  const float* wp2  = (const float*)d_in[17];
  const float* bp2  = (const float*)d_in[18];
  const float* wa1  = (const float*)d_in[19];
  const float* ba1  = (const float*)d_in[20];
  const float* wa2  = (const float*)d_in[21];
  const float* ba2  = (const float*)d_in[22];
  const float* wo   = (const float*)d_in[23];
  const float* bo   = (const float*)d_in[24];
  const float* wr   = (const float*)d_in[25];
  const float* br   = (const float*)d_in[26];
  float* out = (float*)d_out;
  (void)in_sizes; (void)n_in; (void)out_size; (void)ws_size;

  float* ws   = (float*)d_ws;
  float* h1   = ws;                    // (B,256,2048)  4,194,304
  float* ftsv = h1   + 4194304;        // (NPT,256) point-major
  float* q_t  = ftsv + 4194304;        // (NPT,64)
  float* k_t  = q_t  + 1048576;
  float* v_t  = k_t  + 1048576;
  float* fb   = v_t  + 1048576;        // (UP,NPT,64) 4,194,304
  int*   ids  = (int*)(fb + 4194304);  // (NPT,16)

  dim3 blk(256);
  dim3 g4(256, 4), g1(256, 1);

  // h1 = relu(w1 @ [fq;fk] + b1)
  gemm_k<0,0,true ,false><<<g4, blk, 0, stream>>>(w1,  b1,  fq,  fk, h1,  256, 512, 256, 256, 256, 0);
  // ftsv = w2 @ h1 + b2
  gemm_k<0,1,false,false><<<g4, blk, 0, stream>>>(w2,  b2,  h1,  fq, ftsv,256, 256, 256, 256, 256, 0);
  // ftsv += wres @ [fq;fk] + bres
  gemm_k<0,1,false,true ><<<g4, blk, 0, stream>>>(wres,bres,fq,  fk, ftsv,256, 512, 256, 256, 256, 0);
  // q,k,v projections (point-major outputs)
  gemm_k<0,1,false,false><<<g1, blk, 0, stream>>>(wq,  bq,  fq,  fq, q_t, 64,  256, 256, 256, 256, 0);
  gemm_k<0,1,false,false><<<g1, blk, 0, stream>>>(wk,  bk,  fk,  fk, k_t, 64,  256, 256, 256, 256, 0);
  gemm_k<1,1,false,false><<<g1, blk, 0, stream>>>(wv,  bv,  ftsv,ftsv,v_t,64,  256, 256, 256, 256, 0);
  // knn
  knn_k<<<dim3(1024), blk, 0, stream>>>(xyz, ids);
  // fused attention -> fb
  attn_k<<<dim3(NPT), blk, 0, stream>>>(q_t, k_t, v_t, ids, xyz,
                                        wp1, bp1, wp2, bp2, wa1, ba1, wa2, ba2, fb);
  // out[:, :, i*2048:(i+1)*2048] = wo_i @ f_i + bo_i + wr_i @ ftsv + br_i
  for (int i = 0; i < UP_; ++i) {
    gemm_k<1,2,false,false><<<g4, blk, 0, stream>>>(wo + (size_t)i*256*64, bo + i*256,
                                                    fb + (size_t)i*NPT*64, fb, out,
                                                    256, 64, 64, 64, 64, i*2048);
    gemm_k<1,2,false,true ><<<g4, blk, 0, stream>>>(wr + (size_t)i*256*256, br + i*256,
                                                    ftsv, ftsv, out,
                                                    256, 256, 256, 256, 256, i*2048);
  }
}

// Round 2
// 892.900 us; speedup vs baseline: 7.4648x; 7.4648x over previous
//
#include <hip/hip_runtime.h>
#include <hip/hip_bf16.h>

// Problem constants
#define B_  8
#define D_  256
#define M_  2048
#define DT_ 64
#define KT_ 16
#define UP_ 4
#define NPT (B_ * M_)   // 16384 total points

typedef short bfrag __attribute__((ext_vector_type(8)));   // 8 bf16 (4 VGPRs)
typedef float ffrag __attribute__((ext_vector_type(4)));   // 4 fp32 acc

static __device__ inline unsigned short f2bf(float x) {
  unsigned int u = __float_as_uint(x);
  unsigned int r = (u + 0x7fffu + ((u >> 16) & 1u)) >> 16;   // RNE
  return (unsigned short)r;
}
static __device__ inline float bf2f(unsigned short u) {
  return __uint_as_float(((unsigned int)u) << 16);
}

// ---------------------------------------------------------------------------
// Generic tiled fp32 GEMM (unchanged from passing round-0 kernel)
// ---------------------------------------------------------------------------
template<int XM, int YM, bool RELU, bool ADDY>
__global__ __launch_bounds__(256)
void gemm_k(const float* __restrict__ W, const float* __restrict__ Bv,
            const float* __restrict__ X0, const float* __restrict__ X1,
            float* __restrict__ Y,
            int OC, int IC, int split, int ld0, int ld1, int out_off)
{
  __shared__ float sWt[16][68];
  __shared__ float sX[16][68];
  const int t  = threadIdx.x;
  const int n0 = blockIdx.x * 64;
  const int o0 = blockIdx.y * 64;
  const int b  = n0 >> 11;
  const int m0 = n0 & 2047;
  const int oi = (t >> 4) << 2;
  const int ni = (t & 15) << 2;
  float acc[4][4] = {{0.f}};

  for (int k0 = 0; k0 < IC; k0 += 16) {
    {
      int o = t >> 2, kk = (t & 3) << 2;
      const float4 wv = *reinterpret_cast<const float4*>(W + (size_t)(o0 + o) * IC + k0 + kk);
      sWt[kk + 0][o] = wv.x; sWt[kk + 1][o] = wv.y;
      sWt[kk + 2][o] = wv.z; sWt[kk + 3][o] = wv.w;
    }
    #pragma unroll
    for (int r = 0; r < 4; ++r) {
      int kk = (t >> 6) + r * 4;
      int nn = t & 63;
      int c  = k0 + kk;
      float v;
      if (XM == 0) {
        const float* Xp = (c < split) ? (X0 + ((size_t)b * ld0 + c) * 2048)
                                      : (X1 + ((size_t)b * ld1 + (c - split)) * 2048);
        v = Xp[m0 + nn];
      } else {
        int nidx = n0 + nn;
        v = (c < split) ? X0[(size_t)nidx * ld0 + c]
                        : X1[(size_t)nidx * ld1 + (c - split)];
      }
      sX[kk][nn] = v;
    }
    __syncthreads();
    #pragma unroll
    for (int kk = 0; kk < 16; ++kk) {
      float4 wv = *reinterpret_cast<const float4*>(&sWt[kk][oi]);
      float4 xv = *reinterpret_cast<const float4*>(&sX[kk][ni]);
      float w[4] = {wv.x, wv.y, wv.z, wv.w};
      float x[4] = {xv.x, xv.y, xv.z, xv.w};
      #pragma unroll
      for (int i2 = 0; i2 < 4; ++i2)
        #pragma unroll
        for (int j = 0; j < 4; ++j)
          acc[i2][j] = fmaf(w[i2], x[j], acc[i2][j]);
    }
    __syncthreads();
  }

  #pragma unroll
  for (int i2 = 0; i2 < 4; ++i2) {
    int o = o0 + oi + i2;
    float bias = Bv[o];
    #pragma unroll
    for (int j = 0; j < 4; ++j) {
      int nn = ni + j;
      float v = acc[i2][j] + bias;
      if (RELU) v = fmaxf(v, 0.f);
      size_t idx;
      if (YM == 0)      idx = ((size_t)b * OC + o) * 2048 + (m0 + nn);
      else if (YM == 1) idx = (size_t)(n0 + nn) * OC + o;
      else              idx = ((size_t)b * 256 + o) * 8192 + out_off + (m0 + nn);
      if (ADDY) Y[idx] += v; else Y[idx] = v;
    }
  }
}

// ---------------------------------------------------------------------------
// KNN (unchanged, passing)
// ---------------------------------------------------------------------------
__global__ __launch_bounds__(256)
void knn_k(const float* __restrict__ xyz, int* __restrict__ ids)
{
  __shared__ float sx[2048], sy[2048], sz[2048], ss[2048];
  const int blk = blockIdx.x;
  const int b   = blk >> 7;
  const int mg  = blk & 127;
  const int t   = threadIdx.x;
  const float* xb = xyz + (size_t)b * 2048 * 3;
  for (int i = t; i < 2048; i += 256) {
    float x = xb[3 * i], y = xb[3 * i + 1], z = xb[3 * i + 2];
    sx[i] = x; sy[i] = y; sz[i] = z;
    ss[i] = x * x + y * y + z * z;
  }
  __syncthreads();
  const int wave = t >> 6, lane = t & 63;
  for (int qi = 0; qi < 4; ++qi) {
    const int m = mg * 16 + wave * 4 + qi;
    const float xm = sx[m], ym = sy[m], zm = sz[m], sqm = ss[m];
    float d[32];
    #pragma unroll
    for (int j = 0; j < 32; ++j) {
      int nn = lane + 64 * j;
      d[j] = sqm + ss[nn] - 2.f * (sx[nn] * xm + sy[nn] * ym + sz[nn] * zm);
    }
    int* outp = ids + ((size_t)b * 2048 + m) * 16;
    for (int it = 0; it < 16; ++it) {
      float bd = 3.4e38f; int bn = 0x7fffffff;
      #pragma unroll
      for (int j = 0; j < 32; ++j) {
        int nn = lane + 64 * j;
        if (d[j] < bd) { bd = d[j]; bn = nn; }
      }
      #pragma unroll
      for (int off = 32; off > 0; off >>= 1) {
        float od = __shfl_xor(bd, off, 64);
        int   on = __shfl_xor(bn, off, 64);
        if (od < bd || (od == bd && on < bn)) { bd = od; bn = on; }
      }
      if ((bn & 63) == lane) {
        #pragma unroll
        for (int j = 0; j < 32; ++j) if (j == (bn >> 6)) d[j] = 3.4e38f;
      }
      if (lane == 0) outp[it] = bn;
    }
  }
}

// ---------------------------------------------------------------------------
// Convert attention weights to bf16 (layout preserved)
// wa1: (UP,256,64) -> w1bf ; wa2: (UP,64,256) -> w2bf
// ---------------------------------------------------------------------------
__global__ __launch_bounds__(256)
void wcvt_k(const float* __restrict__ wa1, const float* __restrict__ wa2,
            unsigned short* __restrict__ w1bf, unsigned short* __restrict__ w2bf)
{
  int i = blockIdx.x * 256 + threadIdx.x;   // 65536 of each
  w1bf[i] = f2bf(wa1[i]);
  w2bf[i] = f2bf(wa2[i]);
}

// ---------------------------------------------------------------------------
// prep: pos-MLP + gather; materialize a0 = q - k_nbr + pos, vp = v_nbr + pos
// as bf16, point-major [col][64] where col = n*16 + nbr. One block per point.
// ---------------------------------------------------------------------------
__global__ __launch_bounds__(256)
void prep_k(const float* __restrict__ q_t, const float* __restrict__ k_t,
            const float* __restrict__ v_t, const int* __restrict__ idsp,
            const float* __restrict__ xyz,
            const float* __restrict__ wp1, const float* __restrict__ bp1,
            const float* __restrict__ wp2, const float* __restrict__ bp2,
            unsigned short* __restrict__ a0g, unsigned short* __restrict__ vpg)
{
  const int n = blockIdx.x;
  const int b = n >> 11;
  const int t = threadIdx.x;
  __shared__ float s_t1[64][17], s_pos[64][17];
  __shared__ int   s_id[16];
  __shared__ float s_pr[3][16];

  if (t < 16) s_id[t] = idsp[(size_t)n * 16 + t];
  __syncthreads();
  if (t < 48) {
    int k = t & 15, c = t >> 4;
    s_pr[c][k] = xyz[((size_t)b * 2048 + s_id[k]) * 3 + c] - xyz[(size_t)n * 3 + c];
  }
  __syncthreads();
  #pragma unroll
  for (int r = 0; r < 4; ++r) {
    int idx = r * 256 + t, dt = idx >> 4, k = idx & 15;
    float v = wp1[dt * 3] * s_pr[0][k] + wp1[dt * 3 + 1] * s_pr[1][k]
            + wp1[dt * 3 + 2] * s_pr[2][k] + bp1[dt];
    s_t1[dt][k] = fmaxf(v, 0.f);
  }
  __syncthreads();
  #pragma unroll
  for (int r = 0; r < 4; ++r) {
    int idx = r * 256 + t, o = idx >> 4, k = idx & 15;
    float acc = bp2[o];
    for (int c = 0; c < 64; ++c) acc = fmaf(wp2[o * 64 + c], s_t1[c][k], acc);
    s_pos[o][k] = acc;
  }
  __syncthreads();

  const int k  = t >> 4;         // neighbor 0..15
  const int c0 = (t & 15) * 4;   // channel base
  const int nb = s_id[k];
  const float4 qv = *reinterpret_cast<const float4*>(q_t + (size_t)n * 64 + c0);
  const float4 kv = *reinterpret_cast<const float4*>(k_t + ((size_t)b * 2048 + nb) * 64 + c0);
  const float4 vv = *reinterpret_cast<const float4*>(v_t + ((size_t)b * 2048 + nb) * 64 + c0);
  float p0 = s_pos[c0 + 0][k], p1 = s_pos[c0 + 1][k];
  float p2 = s_pos[c0 + 2][k], p3 = s_pos[c0 + 3][k];
  size_t colb = ((size_t)n * 16 + k) * 64 + c0;
  ushort4 av, pv;
  av.x = f2bf(qv.x - kv.x + p0); av.y = f2bf(qv.y - kv.y + p1);
  av.z = f2bf(qv.z - kv.z + p2); av.w = f2bf(qv.w - kv.w + p3);
  pv.x = f2bf(vv.x + p0); pv.y = f2bf(vv.y + p1);
  pv.z = f2bf(vv.z + p2); pv.w = f2bf(vv.w + p3);
  *reinterpret_cast<ushort4*>(a0g + colb) = av;
  *reinterpret_cast<ushort4*>(vpg + colb) = pv;
}

// ---------------------------------------------------------------------------
// MFMA attention: grid (1024, UP). Block 256 thr = 4 independent waves.
// Wave handles 64 columns (4 points). Transposed GEMMs:
//   h^T = a0^T(64col x 64c) . W1^T(c x 256o)   [relu+bias, per 32-o chunk]
//   a2^T += h^T(col x o) . W2^T(o x 64dt)
// Softmax over the 16 rows (=neighbors) of each m-frag, in-register.
// ---------------------------------------------------------------------------
__global__ __launch_bounds__(256)
void attn_mfma_k(const unsigned short* __restrict__ a0g,
                 const unsigned short* __restrict__ vpg,
                 const unsigned short* __restrict__ w1bf,
                 const unsigned short* __restrict__ w2bf,
                 const float* __restrict__ ba1, const float* __restrict__ ba2,
                 float* __restrict__ fb)
{
  const int up   = blockIdx.y;
  const int wid  = threadIdx.x >> 6;
  const int lane = threadIdx.x & 63;
  const int l15  = lane & 15;
  const int lg   = lane >> 4;
  const int m0   = blockIdx.x * 256 + wid * 64;   // global column base

  __shared__ unsigned short hb_all[4][2560];      // 64 rows x 80B per wave
  unsigned short* hb = hb_all[wid];

  const unsigned short* W1 = w1bf + up * 16384;   // [o][c], c contiguous
  const unsigned short* W2 = w2bf + up * 16384;   // [dt][o], o contiguous
  const float* B1 = ba1 + up * 256;
  const float* B2 = ba2 + up * 64;

  // a0 A-fragments: lane holds col = m0+mf*16+l15, k = kf*32 + lg*8 .. +7
  bfrag afr[4][2];
  #pragma unroll
  for (int mf = 0; mf < 4; ++mf)
    #pragma unroll
    for (int kf = 0; kf < 2; ++kf)
      afr[mf][kf] = *reinterpret_cast<const bfrag*>(
          a0g + (size_t)(m0 + mf * 16 + l15) * 64 + kf * 32 + lg * 8);

  ffrag acc2[4][4];
  #pragma unroll
  for (int mf = 0; mf < 4; ++mf)
    #pragma unroll
    for (int nf = 0; nf < 4; ++nf)
      acc2[mf][nf] = (ffrag){0.f, 0.f, 0.f, 0.f};

  for (int oc = 0; oc < 8; ++oc) {
    // W1^T B-frags: B[c][o] = W1[o*64+c]; lane col o = oc*32+nf*16+l15
    bfrag w1f[2][2];
    #pragma unroll
    for (int nf = 0; nf < 2; ++nf)
      #pragma unroll
      for (int kf = 0; kf < 2; ++kf)
        w1f[nf][kf] = *reinterpret_cast<const bfrag*>(
            W1 + (size_t)(oc * 32 + nf * 16 + l15) * 64 + kf * 32 + lg * 8);
    float b1v[2] = { B1[oc * 32 + l15], B1[oc * 32 + 16 + l15] };

    ffrag acc1[4][2];
    #pragma unroll
    for (int mf = 0; mf < 4; ++mf)
      #pragma unroll
      for (int nf = 0; nf < 2; ++nf)
        acc1[mf][nf] = (ffrag){0.f, 0.f, 0.f, 0.f};
    #pragma unroll
    for (int mf = 0; mf < 4; ++mf)
      #pragma unroll
      for (int nf = 0; nf < 2; ++nf)
        #pragma unroll
        for (int kf = 0; kf < 2; ++kf)
          acc1[mf][nf] = __builtin_amdgcn_mfma_f32_16x16x32_bf16(
              afr[mf][kf], w1f[nf][kf], acc1[mf][nf], 0, 0, 0);

    // relu + bias, write h (bf16) transposed into wave-local swizzled LDS
    #pragma unroll
    for (int mf = 0; mf < 4; ++mf)
      #pragma unroll
      for (int nf = 0; nf < 2; ++nf)
        #pragma unroll
        for (int i = 0; i < 4; ++i) {
          float v = fmaxf(acc1[mf][nf][i] + b1v[nf], 0.f);
          int r = mf * 16 + lg * 4 + i;     // local column index
          int o = nf * 16 + l15;            // o within chunk [0,32)
          hb[r * 40 + (((o >> 3) ^ (r & 3)) << 3) + (o & 7)] = f2bf(v);
        }

    // layer 2: A = h^T rows (k = o, 8 contiguous), B = W2^T
    bfrag w2f[4];
    #pragma unroll
    for (int nf = 0; nf < 4; ++nf)
      w2f[nf] = *reinterpret_cast<const bfrag*>(
          W2 + (size_t)(nf * 16 + l15) * 256 + oc * 32 + lg * 8);
    #pragma unroll
    for (int mf = 0; mf < 4; ++mf) {
      int r = mf * 16 + l15;
      bfrag hf = *reinterpret_cast<const bfrag*>(hb + r * 40 + ((lg ^ (r & 3)) << 3));
      #pragma unroll
      for (int nf = 0; nf < 4; ++nf)
        acc2[mf][nf] = __builtin_amdgcn_mfma_f32_16x16x32_bf16(
            hf, w2f[nf], acc2[mf][nf], 0, 0, 0);
    }
  }

  // epilogue: bias+scale, softmax over 16 rows (= neighbors), weighted vp sum
  #pragma unroll
  for (int mf = 0; mf < 4; ++mf) {
    float fsel = 0.f;
    #pragma unroll
    for (int nf = 0; nf < 4; ++nf) {
      float b2v = B2[nf * 16 + l15];
      float v[4];
      #pragma unroll
      for (int i = 0; i < 4; ++i) v[i] = (acc2[mf][nf][i] + b2v) * 0.125f;
      float mx = fmaxf(fmaxf(v[0], v[1]), fmaxf(v[2], v[3]));
      mx = fmaxf(mx, __shfl_xor(mx, 16, 64));
      mx = fmaxf(mx, __shfl_xor(mx, 32, 64));
      float e[4], s = 0.f;
      #pragma unroll
      for (int i = 0; i < 4; ++i) { e[i] = exp2f((v[i] - mx) * 1.44269504088896f); s += e[i]; }
      s += __shfl_xor(s, 16, 64);
      s += __shfl_xor(s, 32, 64);
      float inv = 1.f / s;
      float fp = 0.f;
      #pragma unroll
      for (int i = 0; i < 4; ++i) {
        int col = m0 + mf * 16 + lg * 4 + i;
        float vpv = bf2f(vpg[(size_t)col * 64 + nf * 16 + l15]);
        fp = fmaf(e[i] * inv, vpv, fp);
      }
      fp += __shfl_xor(fp, 16, 64);
      fp += __shfl_xor(fp, 32, 64);
      if (lg == nf) fsel = fp;
    }
    int pt = blockIdx.x * 16 + wid * 4 + mf;
    fb[((size_t)up * NPT + pt) * 64 + lane] = fsel;
  }
}

// ---------------------------------------------------------------------------
extern "C" void kernel_launch(void* const* d_in, const int* in_sizes, int n_in,
                              void* d_out, int out_size, void* d_ws, size_t ws_size,
                              hipStream_t stream)
{
  const float* fq   = (const float*)d_in[0];
  const float* fk   = (const float*)d_in[1];
  const float* xyz  = (const float*)d_in[2];
  const float* w1   = (const float*)d_in[3];
  const float* b1   = (const float*)d_in[4];
  const float* w2   = (const float*)d_in[5];
  const float* b2   = (const float*)d_in[6];
  const float* wres = (const float*)d_in[7];
  const float* bres = (const float*)d_in[8];
  const float* wq   = (const float*)d_in[9];
  const float* bq   = (const float*)d_in[10];
  const float* wk   = (const float*)d_in[11];
  const float* bk   = (const float*)d_in[12];
  const float* wv   = (const float*)d_in[13];
  const float* bv   = (const float*)d_in[14];
  const float* wp1  = (const float*)d_in[15];
  const float* bp1  = (const float*)d_in[16];
  const float* wp2  = (const float*)d_in[17];
  const float* bp2  = (const float*)d_in[18];
  const float* wa1  = (const float*)d_in[19];
  const float* ba1  = (const float*)d_in[20];
  const float* wa2  = (const float*)d_in[21];
  const float* ba2  = (const float*)d_in[22];
  const float* wo   = (const float*)d_in[23];
  const float* bo   = (const float*)d_in[24];
  const float* wr   = (const float*)d_in[25];
  const float* br   = (const float*)d_in[26];
  float* out = (float*)d_out;
  (void)in_sizes; (void)n_in; (void)out_size; (void)ws_size;

  float* ws   = (float*)d_ws;
  float* h1   = ws;                      // 4,194,304 f  (reused as fb later)
  float* ftsv = h1 + 4194304;            // 4,194,304 f
  float* q_t  = ftsv + 4194304;          // 1,048,576 f
  float* k_t  = q_t + 1048576;
  float* v_t  = k_t + 1048576;
  int*   ids  = (int*)(v_t + 1048576);   // 262,144 int
  unsigned short* w1bf = (unsigned short*)(ids + 262144);   // 65,536 us
  unsigned short* w2bf = w1bf + 65536;                      // 65,536 us
  unsigned short* a0g  = w2bf + 65536;                      // 16,777,216 us
  unsigned short* vpg  = a0g + 16777216;                    // 16,777,216 us
  float* fb = h1;                        // alias: h1 dead after gemm #2

  dim3 blk(256);
  dim3 g4(256, 4), g1(256, 1);

  gemm_k<0,0,true ,false><<<g4, blk, 0, stream>>>(w1,  b1,  fq,  fk, h1,  256, 512, 256, 256, 256, 0);
  gemm_k<0,1,false,false><<<g4, blk, 0, stream>>>(w2,  b2,  h1,  fq, ftsv,256, 256, 256, 256, 256, 0);
  gemm_k<0,1,false,true ><<<g4, blk, 0, stream>>>(wres,bres,fq,  fk, ftsv,256, 512, 256, 256, 256, 0);
  gemm_k<0,1,false,false><<<g1, blk, 0, stream>>>(wq,  bq,  fq,  fq, q_t, 64,  256, 256, 256, 256, 0);
  gemm_k<0,1,false,false><<<g1, blk, 0, stream>>>(wk,  bk,  fk,  fk, k_t, 64,  256, 256, 256, 256, 0);
  gemm_k<1,1,false,false><<<g1, blk, 0, stream>>>(wv,  bv,  ftsv,ftsv,v_t,64,  256, 256, 256, 256, 0);
  knn_k<<<dim3(1024), blk, 0, stream>>>(xyz, ids);
  wcvt_k<<<dim3(256), blk, 0, stream>>>(wa1, wa2, w1bf, w2bf);
  prep_k<<<dim3(NPT), blk, 0, stream>>>(q_t, k_t, v_t, ids, xyz,
                                        wp1, bp1, wp2, bp2, a0g, vpg);
  attn_mfma_k<<<dim3(1024, UP_), blk, 0, stream>>>(a0g, vpg, w1bf, w2bf, ba1, ba2, fb);
  for (int i = 0; i < UP_; ++i) {
    gemm_k<1,2,false,false><<<g4, blk, 0, stream>>>(wo + (size_t)i*256*64, bo + i*256,
                                                    fb + (size_t)i*NPT*64, fb, out,
                                                    256, 64, 64, 64, 64, i*2048);
    gemm_k<1,2,false,true ><<<g4, blk, 0, stream>>>(wr + (size_t)i*256*256, br + i*256,
                                                    ftsv, ftsv, out,
                                                    256, 256, 256, 256, 256, i*2048);
  }
}

// Round 3
// 560.855 us; speedup vs baseline: 11.8842x; 1.5920x over previous
//
#include <hip/hip_runtime.h>
#include <hip/hip_bf16.h>

#define B_  8
#define D_  256
#define M_  2048
#define DT_ 64
#define KT_ 16
#define UP_ 4
#define NPT (B_ * M_)   // 16384 total points

typedef short bfrag __attribute__((ext_vector_type(8)));   // 8 bf16 (4 VGPRs)
typedef float ffrag __attribute__((ext_vector_type(4)));   // 4 fp32 acc

static __device__ inline unsigned short f2bf(float x) {
  unsigned int u = __float_as_uint(x);
  unsigned int r = (u + 0x7fffu + ((u >> 16) & 1u)) >> 16;   // RNE
  return (unsigned short)r;
}
static __device__ inline float bf2f(unsigned short u) {
  return __uint_as_float(((unsigned int)u) << 16);
}

__device__ __forceinline__ void gload16(const unsigned short* g, unsigned short* l) {
  __builtin_amdgcn_global_load_lds(
      (const __attribute__((address_space(1))) unsigned int*)(const void*)g,
      (__attribute__((address_space(3))) unsigned int*)(void*)l, 16, 0, 0);
}

// ---------------------------------------------------------------------------
// bf16 MFMA GEMM. Tile: 128 n x 64 o x 64 k. 256 thr = 4 waves, each 64x32
// (non-SWAP) or 32o x 64n (SWAP). A (activations) point-major [n][ld],
// W [o][ld], both k-contiguous bf16. 3-way K-split on A, 2-way on W.
// YOUT: 0 = bf16 [n][OC], 1 = fp32 [n][OC], 2 = fp32 (B,256,8192) at out_off
// (YOUT=2 requires SWAP so columns are lane-contiguous).
// ---------------------------------------------------------------------------
template<int YOUT, bool RELU, bool SWAP>
__global__ __launch_bounds__(256)
void bgemm_k(const unsigned short* __restrict__ A0, const unsigned short* __restrict__ A1,
             const unsigned short* __restrict__ A2, int ae1, int ae2,
             int lda0, int lda1, int lda2,
             const unsigned short* __restrict__ W0, const unsigned short* __restrict__ W1,
             int be1, int ldw0, int ldw1,
             const float* __restrict__ Bv, void* __restrict__ Yp,
             int IC, int OC, int out_off)
{
  __shared__ unsigned short sX[128 * 64];
  __shared__ unsigned short sW[64 * 64];
  const int t    = threadIdx.x;
  const int lane = t & 63, wid = t >> 6;
  const int l15  = lane & 15, lg = lane >> 4;
  const int n0   = blockIdx.x * 128;
  const int o0   = blockIdx.y * 64;
  constexpr int MF = SWAP ? 2 : 4;
  constexpr int NF = SWAP ? 4 : 2;
  const int wa = wid & 1;    // non-swap: n 64-half ; swap: o 32-half
  const int wb = wid >> 1;   // non-swap: o 32-half ; swap: n 64-half

  ffrag acc[MF][NF];
  #pragma unroll
  for (int mf = 0; mf < MF; ++mf)
    #pragma unroll
    for (int nf = 0; nf < NF; ++nf)
      acc[mf][nf] = (ffrag){0.f, 0.f, 0.f, 0.f};

  for (int k0 = 0; k0 < IC; k0 += 64) {
    const unsigned short* Ap; int lda, ka;
    if (k0 < ae1)      { Ap = A0; lda = lda0; ka = 0;   }
    else if (k0 < ae2) { Ap = A1; lda = lda1; ka = ae1; }
    else               { Ap = A2; lda = lda2; ka = ae2; }
    const unsigned short* Wp; int ldw, kw;
    if (k0 < be1) { Wp = W0; ldw = ldw0; kw = 0;   }
    else          { Wp = W1; ldw = ldw1; kw = be1; }
    #pragma unroll
    for (int it = 0; it < 4; ++it) {
      int idx = it * 256 + t;
      int r = idx >> 3;
      int e = ((idx & 7) * 8) ^ ((r & 7) << 3);
      gload16(Ap + (size_t)(n0 + r) * lda + (k0 - ka) + e, sX + idx * 8);
    }
    #pragma unroll
    for (int it = 0; it < 2; ++it) {
      int idx = it * 256 + t;
      int r = idx >> 3;
      int e = ((idx & 7) * 8) ^ ((r & 7) << 3);
      gload16(Wp + (size_t)(o0 + r) * ldw + (k0 - kw) + e, sW + idx * 8);
    }
    __syncthreads();
    bfrag af[MF][2], bfr[NF][2];
    #pragma unroll
    for (int mf = 0; mf < MF; ++mf)
      #pragma unroll
      for (int kf = 0; kf < 2; ++kf) {
        int r = SWAP ? (wa * 32 + mf * 16 + l15) : (wa * 64 + mf * 16 + l15);
        int e = (kf * 32 + lg * 8) ^ ((r & 7) << 3);
        af[mf][kf] = *reinterpret_cast<const bfrag*>((SWAP ? sW : sX) + r * 64 + e);
      }
    #pragma unroll
    for (int nf = 0; nf < NF; ++nf)
      #pragma unroll
      for (int kf = 0; kf < 2; ++kf) {
        int r = SWAP ? (wb * 64 + nf * 16 + l15) : (wb * 32 + nf * 16 + l15);
        int e = (kf * 32 + lg * 8) ^ ((r & 7) << 3);
        bfr[nf][kf] = *reinterpret_cast<const bfrag*>((SWAP ? sX : sW) + r * 64 + e);
      }
    #pragma unroll
    for (int kf = 0; kf < 2; ++kf)
      #pragma unroll
      for (int mf = 0; mf < MF; ++mf)
        #pragma unroll
        for (int nf = 0; nf < NF; ++nf)
          acc[mf][nf] = __builtin_amdgcn_mfma_f32_16x16x32_bf16(
              af[mf][kf], bfr[nf][kf], acc[mf][nf], 0, 0, 0);
    __syncthreads();
  }

  if (!SWAP) {
    #pragma unroll
    for (int mf = 0; mf < MF; ++mf) {
      int n = n0 + wa * 64 + mf * 16 + lg * 4;
      #pragma unroll
      for (int nf = 0; nf < NF; ++nf) {
        int o = o0 + wb * 32 + nf * 16 + l15;
        float bias = Bv[o];
        #pragma unroll
        for (int i = 0; i < 4; ++i) {
          float v = acc[mf][nf][i] + bias;
          if (RELU) v = fmaxf(v, 0.f);
          size_t yi = (size_t)(n + i) * OC + o;
          if (YOUT == 0) ((unsigned short*)Yp)[yi] = f2bf(v);
          else           ((float*)Yp)[yi] = v;
        }
      }
    }
  } else {
    #pragma unroll
    for (int mf = 0; mf < MF; ++mf)
      #pragma unroll
      for (int i = 0; i < 4; ++i) {
        int o = o0 + wa * 32 + mf * 16 + lg * 4 + i;
        float bias = Bv[o];
        #pragma unroll
        for (int nf = 0; nf < NF; ++nf) {
          int n = n0 + wb * 64 + nf * 16 + l15;
          float v = acc[mf][nf][i] + bias;
          int b = n >> 11, m = n & 2047;
          ((float*)Yp)[((size_t)b * 256 + o) * 8192 + out_off + m] = v;
        }
      }
  }
}

// ---------------------------------------------------------------------------
// Convert ALL weights to bf16 (layouts preserved) + fused bias sums.
// wreg layout (elements): w1b:0  w2b:131072  wresb:196608  wqb:327680
//   wkb:344064  wvb:360448  wob:376832  wrb:442368  wa1b:704512  wa2b:770048
// bsum: [0,1024) = bo+br per up; [1024,1280) = b2+bres
// ---------------------------------------------------------------------------
__global__ __launch_bounds__(256)
void wcvt_all_k(const float* __restrict__ w1, const float* __restrict__ w2,
                const float* __restrict__ wres, const float* __restrict__ wq,
                const float* __restrict__ wk, const float* __restrict__ wv,
                const float* __restrict__ wo, const float* __restrict__ wr,
                const float* __restrict__ wa1, const float* __restrict__ wa2,
                const float* __restrict__ bo, const float* __restrict__ br,
                const float* __restrict__ b2, const float* __restrict__ bres,
                unsigned short* __restrict__ wreg, float* __restrict__ bsum)
{
  int i = blockIdx.x * 256 + threadIdx.x;
  if      (i < 131072) wreg[i] = f2bf(w1[i]);
  else if (i < 196608) wreg[i] = f2bf(w2[i - 131072]);
  else if (i < 327680) wreg[i] = f2bf(wres[i - 196608]);
  else if (i < 344064) wreg[i] = f2bf(wq[i - 327680]);
  else if (i < 360448) wreg[i] = f2bf(wk[i - 344064]);
  else if (i < 376832) wreg[i] = f2bf(wv[i - 360448]);
  else if (i < 442368) wreg[i] = f2bf(wo[i - 376832]);
  else if (i < 704512) wreg[i] = f2bf(wr[i - 442368]);
  else if (i < 770048) wreg[i] = f2bf(wa1[i - 704512]);
  else if (i < 835584) wreg[i] = f2bf(wa2[i - 770048]);
  else {
    int j = i - 835584;
    if (j < 1024)      bsum[j] = bo[j] + br[j];
    else if (j < 1280) bsum[j] = b2[j - 1024] + bres[j - 1024];
  }
}

// ---------------------------------------------------------------------------
// Transpose-convert (B,256,2048) fp32 -> point-major [n][256] bf16 (fq & fk)
// grid (32, 4, 16): z = b*2 + src
// ---------------------------------------------------------------------------
__global__ __launch_bounds__(256)
void cvtT_k(const float* __restrict__ fq, const float* __restrict__ fk,
            unsigned short* __restrict__ xqb, unsigned short* __restrict__ xkb)
{
  const int t  = threadIdx.x;
  const int m0 = blockIdx.x * 64;
  const int c0 = blockIdx.y * 64;
  const int z  = blockIdx.z;
  const int b  = z >> 1;
  const float* src = (z & 1) ? fk : fq;
  unsigned short* dst = (z & 1) ? xkb : xqb;
  __shared__ unsigned short sT[64][68];
  #pragma unroll
  for (int it = 0; it < 16; ++it) {
    int idx = it * 256 + t;
    int c = idx >> 6, m = idx & 63;
    sT[m][c] = f2bf(src[((size_t)b * 256 + c0 + c) * 2048 + m0 + m]);
  }
  __syncthreads();
  #pragma unroll
  for (int it = 0; it < 8; ++it) {
    int idx = it * 256 + t;
    int n = idx >> 5, cw = idx & 31;
    unsigned int w = *reinterpret_cast<const unsigned int*>(&sT[n][cw * 2]);
    *reinterpret_cast<unsigned int*>(&dst[((size_t)b * 2048 + m0 + n) * 256 + c0 + cw * 2]) = w;
  }
}

// ---------------------------------------------------------------------------
// KNN (unchanged, passing)
// ---------------------------------------------------------------------------
__global__ __launch_bounds__(256)
void knn_k(const float* __restrict__ xyz, int* __restrict__ ids)
{
  __shared__ float sx[2048], sy[2048], sz[2048], ss[2048];
  const int blk = blockIdx.x;
  const int b   = blk >> 7;
  const int mg  = blk & 127;
  const int t   = threadIdx.x;
  const float* xb = xyz + (size_t)b * 2048 * 3;
  for (int i = t; i < 2048; i += 256) {
    float x = xb[3 * i], y = xb[3 * i + 1], z = xb[3 * i + 2];
    sx[i] = x; sy[i] = y; sz[i] = z;
    ss[i] = x * x + y * y + z * z;
  }
  __syncthreads();
  const int wave = t >> 6, lane = t & 63;
  for (int qi = 0; qi < 4; ++qi) {
    const int m = mg * 16 + wave * 4 + qi;
    const float xm = sx[m], ym = sy[m], zm = sz[m], sqm = ss[m];
    float d[32];
    #pragma unroll
    for (int j = 0; j < 32; ++j) {
      int nn = lane + 64 * j;
      d[j] = sqm + ss[nn] - 2.f * (sx[nn] * xm + sy[nn] * ym + sz[nn] * zm);
    }
    int* outp = ids + ((size_t)b * 2048 + m) * 16;
    for (int it = 0; it < 16; ++it) {
      float bd = 3.4e38f; int bn = 0x7fffffff;
      #pragma unroll
      for (int j = 0; j < 32; ++j) {
        int nn = lane + 64 * j;
        if (d[j] < bd) { bd = d[j]; bn = nn; }
      }
      #pragma unroll
      for (int off = 32; off > 0; off >>= 1) {
        float od = __shfl_xor(bd, off, 64);
        int   on = __shfl_xor(bn, off, 64);
        if (od < bd || (od == bd && on < bn)) { bd = od; bn = on; }
      }
      if ((bn & 63) == lane) {
        #pragma unroll
        for (int j = 0; j < 32; ++j) if (j == (bn >> 6)) d[j] = 3.4e38f;
      }
      if (lane == 0) outp[it] = bn;
    }
  }
}

// ---------------------------------------------------------------------------
// prep: pos-MLP + gather -> a0, vp bf16 point-major [col][64] (unchanged)
// ---------------------------------------------------------------------------
__global__ __launch_bounds__(256)
void prep_k(const float* __restrict__ q_t, const float* __restrict__ k_t,
            const float* __restrict__ v_t, const int* __restrict__ idsp,
            const float* __restrict__ xyz,
            const float* __restrict__ wp1, const float* __restrict__ bp1,
            const float* __restrict__ wp2, const float* __restrict__ bp2,
            unsigned short* __restrict__ a0g, unsigned short* __restrict__ vpg)
{
  const int n = blockIdx.x;
  const int b = n >> 11;
  const int t = threadIdx.x;
  __shared__ float s_t1[64][17], s_pos[64][17];
  __shared__ int   s_id[16];
  __shared__ float s_pr[3][16];

  if (t < 16) s_id[t] = idsp[(size_t)n * 16 + t];
  __syncthreads();
  if (t < 48) {
    int k = t & 15, c = t >> 4;
    s_pr[c][k] = xyz[((size_t)b * 2048 + s_id[k]) * 3 + c] - xyz[(size_t)n * 3 + c];
  }
  __syncthreads();
  #pragma unroll
  for (int r = 0; r < 4; ++r) {
    int idx = r * 256 + t, dt = idx >> 4, k = idx & 15;
    float v = wp1[dt * 3] * s_pr[0][k] + wp1[dt * 3 + 1] * s_pr[1][k]
            + wp1[dt * 3 + 2] * s_pr[2][k] + bp1[dt];
    s_t1[dt][k] = fmaxf(v, 0.f);
  }
  __syncthreads();
  #pragma unroll
  for (int r = 0; r < 4; ++r) {
    int idx = r * 256 + t, o = idx >> 4, k = idx & 15;
    float acc = bp2[o];
    for (int c = 0; c < 64; ++c) acc = fmaf(wp2[o * 64 + c], s_t1[c][k], acc);
    s_pos[o][k] = acc;
  }
  __syncthreads();

  const int k  = t >> 4;
  const int c0 = (t & 15) * 4;
  const int nb = s_id[k];
  const float4 qv = *reinterpret_cast<const float4*>(q_t + (size_t)n * 64 + c0);
  const float4 kv = *reinterpret_cast<const float4*>(k_t + ((size_t)b * 2048 + nb) * 64 + c0);
  const float4 vv = *reinterpret_cast<const float4*>(v_t + ((size_t)b * 2048 + nb) * 64 + c0);
  float p0 = s_pos[c0 + 0][k], p1 = s_pos[c0 + 1][k];
  float p2 = s_pos[c0 + 2][k], p3 = s_pos[c0 + 3][k];
  size_t colb = ((size_t)n * 16 + k) * 64 + c0;
  ushort4 av, pv;
  av.x = f2bf(qv.x - kv.x + p0); av.y = f2bf(qv.y - kv.y + p1);
  av.z = f2bf(qv.z - kv.z + p2); av.w = f2bf(qv.w - kv.w + p3);
  pv.x = f2bf(vv.x + p0); pv.y = f2bf(vv.y + p1);
  pv.z = f2bf(vv.z + p2); pv.w = f2bf(vv.w + p3);
  *reinterpret_cast<ushort4*>(a0g + colb) = av;
  *reinterpret_cast<ushort4*>(vpg + colb) = pv;
}

// ---------------------------------------------------------------------------
// MFMA attention (same structure as round-1 passing kernel; fb now bf16)
// ---------------------------------------------------------------------------
__global__ __launch_bounds__(256)
void attn_mfma_k(const unsigned short* __restrict__ a0g,
                 const unsigned short* __restrict__ vpg,
                 const unsigned short* __restrict__ w1bf,
                 const unsigned short* __restrict__ w2bf,
                 const float* __restrict__ ba1, const float* __restrict__ ba2,
                 unsigned short* __restrict__ fb)
{
  const int up   = blockIdx.y;
  const int wid  = threadIdx.x >> 6;
  const int lane = threadIdx.x & 63;
  const int l15  = lane & 15;
  const int lg   = lane >> 4;
  const int m0   = blockIdx.x * 256 + wid * 64;

  __shared__ unsigned short hb_all[4][2560];
  unsigned short* hb = hb_all[wid];

  const unsigned short* W1 = w1bf + up * 16384;
  const unsigned short* W2 = w2bf + up * 16384;
  const float* B1 = ba1 + up * 256;
  const float* B2 = ba2 + up * 64;

  bfrag afr[4][2];
  #pragma unroll
  for (int mf = 0; mf < 4; ++mf)
    #pragma unroll
    for (int kf = 0; kf < 2; ++kf)
      afr[mf][kf] = *reinterpret_cast<const bfrag*>(
          a0g + (size_t)(m0 + mf * 16 + l15) * 64 + kf * 32 + lg * 8);

  ffrag acc2[4][4];
  #pragma unroll
  for (int mf = 0; mf < 4; ++mf)
    #pragma unroll
    for (int nf = 0; nf < 4; ++nf)
      acc2[mf][nf] = (ffrag){0.f, 0.f, 0.f, 0.f};

  for (int oc = 0; oc < 8; ++oc) {
    bfrag w1f[2][2];
    #pragma unroll
    for (int nf = 0; nf < 2; ++nf)
      #pragma unroll
      for (int kf = 0; kf < 2; ++kf)
        w1f[nf][kf] = *reinterpret_cast<const bfrag*>(
            W1 + (size_t)(oc * 32 + nf * 16 + l15) * 64 + kf * 32 + lg * 8);
    float b1v[2] = { B1[oc * 32 + l15], B1[oc * 32 + 16 + l15] };

    ffrag acc1[4][2];
    #pragma unroll
    for (int mf = 0; mf < 4; ++mf)
      #pragma unroll
      for (int nf = 0; nf < 2; ++nf)
        acc1[mf][nf] = (ffrag){0.f, 0.f, 0.f, 0.f};
    #pragma unroll
    for (int mf = 0; mf < 4; ++mf)
      #pragma unroll
      for (int nf = 0; nf < 2; ++nf)
        #pragma unroll
        for (int kf = 0; kf < 2; ++kf)
          acc1[mf][nf] = __builtin_amdgcn_mfma_f32_16x16x32_bf16(
              afr[mf][kf], w1f[nf][kf], acc1[mf][nf], 0, 0, 0);

    #pragma unroll
    for (int mf = 0; mf < 4; ++mf)
      #pragma unroll
      for (int nf = 0; nf < 2; ++nf)
        #pragma unroll
        for (int i = 0; i < 4; ++i) {
          float v = fmaxf(acc1[mf][nf][i] + b1v[nf], 0.f);
          int r = mf * 16 + lg * 4 + i;
          int o = nf * 16 + l15;
          hb[r * 40 + (((o >> 3) ^ (r & 3)) << 3) + (o & 7)] = f2bf(v);
        }

    bfrag w2f[4];
    #pragma unroll
    for (int nf = 0; nf < 4; ++nf)
      w2f[nf] = *reinterpret_cast<const bfrag*>(
          W2 + (size_t)(nf * 16 + l15) * 256 + oc * 32 + lg * 8);
    #pragma unroll
    for (int mf = 0; mf < 4; ++mf) {
      int r = mf * 16 + l15;
      bfrag hf = *reinterpret_cast<const bfrag*>(hb + r * 40 + ((lg ^ (r & 3)) << 3));
      #pragma unroll
      for (int nf = 0; nf < 4; ++nf)
        acc2[mf][nf] = __builtin_amdgcn_mfma_f32_16x16x32_bf16(
            hf, w2f[nf], acc2[mf][nf], 0, 0, 0);
    }
  }

  #pragma unroll
  for (int mf = 0; mf < 4; ++mf) {
    float fsel = 0.f;
    #pragma unroll
    for (int nf = 0; nf < 4; ++nf) {
      float b2v = B2[nf * 16 + l15];
      float v[4];
      #pragma unroll
      for (int i = 0; i < 4; ++i) v[i] = (acc2[mf][nf][i] + b2v) * 0.125f;
      float mx = fmaxf(fmaxf(v[0], v[1]), fmaxf(v[2], v[3]));
      mx = fmaxf(mx, __shfl_xor(mx, 16, 64));
      mx = fmaxf(mx, __shfl_xor(mx, 32, 64));
      float e[4], s = 0.f;
      #pragma unroll
      for (int i = 0; i < 4; ++i) { e[i] = exp2f((v[i] - mx) * 1.44269504088896f); s += e[i]; }
      s += __shfl_xor(s, 16, 64);
      s += __shfl_xor(s, 32, 64);
      float inv = 1.f / s;
      float fp = 0.f;
      #pragma unroll
      for (int i = 0; i < 4; ++i) {
        int col = m0 + mf * 16 + lg * 4 + i;
        float vpv = bf2f(vpg[(size_t)col * 64 + nf * 16 + l15]);
        fp = fmaf(e[i] * inv, vpv, fp);
      }
      fp += __shfl_xor(fp, 16, 64);
      fp += __shfl_xor(fp, 32, 64);
      if (lg == nf) fsel = fp;
    }
    int pt = blockIdx.x * 16 + wid * 4 + mf;
    fb[((size_t)up * NPT + pt) * 64 + lane] = f2bf(fsel);
  }
}

// ---------------------------------------------------------------------------
extern "C" void kernel_launch(void* const* d_in, const int* in_sizes, int n_in,
                              void* d_out, int out_size, void* d_ws, size_t ws_size,
                              hipStream_t stream)
{
  const float* fq   = (const float*)d_in[0];
  const float* fk   = (const float*)d_in[1];
  const float* xyz  = (const float*)d_in[2];
  const float* w1   = (const float*)d_in[3];
  const float* b1   = (const float*)d_in[4];
  const float* w2   = (const float*)d_in[5];
  const float* b2   = (const float*)d_in[6];
  const float* wres = (const float*)d_in[7];
  const float* bres = (const float*)d_in[8];
  const float* wq   = (const float*)d_in[9];
  const float* bq   = (const float*)d_in[10];
  const float* wk   = (const float*)d_in[11];
  const float* bk   = (const float*)d_in[12];
  const float* wv   = (const float*)d_in[13];
  const float* bv   = (const float*)d_in[14];
  const float* wp1  = (const float*)d_in[15];
  const float* bp1  = (const float*)d_in[16];
  const float* wp2  = (const float*)d_in[17];
  const float* bp2  = (const float*)d_in[18];
  const float* wa1  = (const float*)d_in[19];
  const float* ba1  = (const float*)d_in[20];
  const float* wa2  = (const float*)d_in[21];
  const float* ba2  = (const float*)d_in[22];
  const float* wo   = (const float*)d_in[23];
  const float* bo   = (const float*)d_in[24];
  const float* wr   = (const float*)d_in[25];
  const float* br   = (const float*)d_in[26];
  float* out = (float*)d_out;
  (void)in_sizes; (void)n_in; (void)out_size; (void)ws_size;

  unsigned short* u    = (unsigned short*)d_ws;
  unsigned short* wreg = u;                       // 835,584
  unsigned short* xqb  = wreg + 835584;           // 4,194,304
  unsigned short* xkb  = xqb  + 4194304;
  unsigned short* ftsb = xkb  + 4194304;
  unsigned short* h1b  = ftsb + 4194304;          // reused as fbb after gemms
  unsigned short* a0g  = h1b  + 4194304;          // 16,777,216
  unsigned short* vpg  = a0g  + 16777216;
  float* q_t  = (float*)(vpg + 16777216);         // 1,048,576 f each
  float* k_t  = q_t + 1048576;
  float* v_t  = k_t + 1048576;
  int*   ids  = (int*)(v_t + 1048576);            // 262,144
  float* bsum = (float*)(ids + 262144);           // 1,280 f

  unsigned short* w1b   = wreg;
  unsigned short* w2b   = wreg + 131072;
  unsigned short* wresb = wreg + 196608;
  unsigned short* wqb   = wreg + 327680;
  unsigned short* wkb   = wreg + 344064;
  unsigned short* wvb   = wreg + 360448;
  unsigned short* wob   = wreg + 376832;
  unsigned short* wrb   = wreg + 442368;
  unsigned short* wa1b  = wreg + 704512;
  unsigned short* wa2b  = wreg + 770048;
  unsigned short* fbb   = h1b;
  const int BIG = 1 << 30;

  dim3 blk(256);

  wcvt_all_k<<<dim3(3269), blk, 0, stream>>>(w1, w2, wres, wq, wk, wv, wo, wr,
                                             wa1, wa2, bo, br, b2, bres, wreg, bsum);
  cvtT_k<<<dim3(32, 4, 16), blk, 0, stream>>>(fq, fk, xqb, xkb);
  knn_k<<<dim3(1024), blk, 0, stream>>>(xyz, ids);

  // h1 = relu(w1 @ [fq;fk] + b1)  -> bf16 [n][256]
  bgemm_k<0, true, false><<<dim3(128, 4), blk, 0, stream>>>(
      xqb, xkb, xkb, 256, BIG, 256, 256, 256,
      w1b, w1b, BIG, 512, 512, b1, h1b, 512, 256, 0);
  // ftsv = [w2|wres] @ [h1;fq;fk] + (b2+bres) -> bf16 [n][256]
  bgemm_k<0, false, false><<<dim3(128, 4), blk, 0, stream>>>(
      h1b, xqb, xkb, 256, 512, 256, 256, 256,
      w2b, wresb, 256, 256, 512, bsum + 1024, ftsb, 768, 256, 0);
  // q, k, v projections -> fp32 [n][64]
  bgemm_k<1, false, false><<<dim3(128, 1), blk, 0, stream>>>(
      xqb, xqb, xqb, BIG, BIG, 256, 256, 256,
      wqb, wqb, BIG, 256, 256, bq, q_t, 256, 64, 0);
  bgemm_k<1, false, false><<<dim3(128, 1), blk, 0, stream>>>(
      xkb, xkb, xkb, BIG, BIG, 256, 256, 256,
      wkb, wkb, BIG, 256, 256, bk, k_t, 256, 64, 0);
  bgemm_k<1, false, false><<<dim3(128, 1), blk, 0, stream>>>(
      ftsb, ftsb, ftsb, BIG, BIG, 256, 256, 256,
      wvb, wvb, BIG, 256, 256, bv, v_t, 256, 64, 0);

  prep_k<<<dim3(NPT), blk, 0, stream>>>(q_t, k_t, v_t, ids, xyz,
                                        wp1, bp1, wp2, bp2, a0g, vpg);
  attn_mfma_k<<<dim3(1024, UP_), blk, 0, stream>>>(a0g, vpg, wa1b, wa2b, ba1, ba2, fbb);

  // out[:, :, i*2048:(i+1)*2048] = [wo_i|wr_i] @ [f_i; ftsv] + (bo_i+br_i)
  for (int i = 0; i < UP_; ++i) {
    bgemm_k<2, false, true><<<dim3(128, 4), blk, 0, stream>>>(
        fbb + (size_t)i * 1048576, ftsb, ftsb, 64, BIG, 64, 256, 256,
        wob + (size_t)i * 16384, wrb + (size_t)i * 65536, 64, 64, 256,
        bsum + i * 256, out, 320, 256, i * 2048);
  }
}

// Round 5
// 527.568 us; speedup vs baseline: 12.6341x; 1.0631x over previous
//
#include <hip/hip_runtime.h>
#include <hip/hip_bf16.h>

#define B_  8
#define D_  256
#define M_  2048
#define DT_ 64
#define KT_ 16
#define UP_ 4
#define NPT (B_ * M_)   // 16384 total points

typedef short bfrag __attribute__((ext_vector_type(8)));   // 8 bf16 (4 VGPRs)
typedef float ffrag __attribute__((ext_vector_type(4)));   // 4 fp32 acc

static __device__ inline unsigned short f2bf(float x) {
  unsigned int u = __float_as_uint(x);
  unsigned int r = (u + 0x7fffu + ((u >> 16) & 1u)) >> 16;   // RNE
  return (unsigned short)r;
}
static __device__ inline float bf2f(unsigned short u) {
  return __uint_as_float(((unsigned int)u) << 16);
}

__device__ __forceinline__ void gload16(const unsigned short* g, unsigned short* l) {
  __builtin_amdgcn_global_load_lds(
      (const __attribute__((address_space(1))) unsigned int*)(const void*)g,
      (__attribute__((address_space(3))) unsigned int*)(void*)l, 16, 0, 0);
}

// ---------------------------------------------------------------------------
// bf16 MFMA GEMM. Tile: 128 n x 64 o x 64 k (verified round-2/3).
// ---------------------------------------------------------------------------
template<int YOUT, bool RELU, bool SWAP>
__global__ __launch_bounds__(256)
void bgemm_k(const unsigned short* __restrict__ A0, const unsigned short* __restrict__ A1,
             const unsigned short* __restrict__ A2, int ae1, int ae2,
             int lda0, int lda1, int lda2,
             const unsigned short* __restrict__ W0, const unsigned short* __restrict__ W1,
             int be1, int ldw0, int ldw1,
             const float* __restrict__ Bv, void* __restrict__ Yp,
             int IC, int OC, int out_off)
{
  __shared__ unsigned short sX[128 * 64];
  __shared__ unsigned short sW[64 * 64];
  const int t    = threadIdx.x;
  const int lane = t & 63, wid = t >> 6;
  const int l15  = lane & 15, lg = lane >> 4;
  const int n0   = blockIdx.x * 128;
  const int o0   = blockIdx.y * 64;
  constexpr int MF = SWAP ? 2 : 4;
  constexpr int NF = SWAP ? 4 : 2;
  const int wa = wid & 1;
  const int wb = wid >> 1;

  ffrag acc[MF][NF];
  #pragma unroll
  for (int mf = 0; mf < MF; ++mf)
    #pragma unroll
    for (int nf = 0; nf < NF; ++nf)
      acc[mf][nf] = (ffrag){0.f, 0.f, 0.f, 0.f};

  for (int k0 = 0; k0 < IC; k0 += 64) {
    const unsigned short* Ap; int lda, ka;
    if (k0 < ae1)      { Ap = A0; lda = lda0; ka = 0;   }
    else if (k0 < ae2) { Ap = A1; lda = lda1; ka = ae1; }
    else               { Ap = A2; lda = lda2; ka = ae2; }
    const unsigned short* Wp; int ldw, kw;
    if (k0 < be1) { Wp = W0; ldw = ldw0; kw = 0;   }
    else          { Wp = W1; ldw = ldw1; kw = be1; }
    #pragma unroll
    for (int it = 0; it < 4; ++it) {
      int idx = it * 256 + t;
      int r = idx >> 3;
      int e = ((idx & 7) * 8) ^ ((r & 7) << 3);
      gload16(Ap + (size_t)(n0 + r) * lda + (k0 - ka) + e, sX + idx * 8);
    }
    #pragma unroll
    for (int it = 0; it < 2; ++it) {
      int idx = it * 256 + t;
      int r = idx >> 3;
      int e = ((idx & 7) * 8) ^ ((r & 7) << 3);
      gload16(Wp + (size_t)(o0 + r) * ldw + (k0 - kw) + e, sW + idx * 8);
    }
    __syncthreads();
    bfrag af[MF][2], bfr[NF][2];
    #pragma unroll
    for (int mf = 0; mf < MF; ++mf)
      #pragma unroll
      for (int kf = 0; kf < 2; ++kf) {
        int r = SWAP ? (wa * 32 + mf * 16 + l15) : (wa * 64 + mf * 16 + l15);
        int e = (kf * 32 + lg * 8) ^ ((r & 7) << 3);
        af[mf][kf] = *reinterpret_cast<const bfrag*>((SWAP ? sW : sX) + r * 64 + e);
      }
    #pragma unroll
    for (int nf = 0; nf < NF; ++nf)
      #pragma unroll
      for (int kf = 0; kf < 2; ++kf) {
        int r = SWAP ? (wb * 64 + nf * 16 + l15) : (wb * 32 + nf * 16 + l15);
        int e = (kf * 32 + lg * 8) ^ ((r & 7) << 3);
        bfr[nf][kf] = *reinterpret_cast<const bfrag*>((SWAP ? sX : sW) + r * 64 + e);
      }
    #pragma unroll
    for (int kf = 0; kf < 2; ++kf)
      #pragma unroll
      for (int mf = 0; mf < MF; ++mf)
        #pragma unroll
        for (int nf = 0; nf < NF; ++nf)
          acc[mf][nf] = __builtin_amdgcn_mfma_f32_16x16x32_bf16(
              af[mf][kf], bfr[nf][kf], acc[mf][nf], 0, 0, 0);
    __syncthreads();
  }

  if (!SWAP) {
    #pragma unroll
    for (int mf = 0; mf < MF; ++mf) {
      int n = n0 + wa * 64 + mf * 16 + lg * 4;
      #pragma unroll
      for (int nf = 0; nf < NF; ++nf) {
        int o = o0 + wb * 32 + nf * 16 + l15;
        float bias = Bv[o];
        #pragma unroll
        for (int i = 0; i < 4; ++i) {
          float v = acc[mf][nf][i] + bias;
          if (RELU) v = fmaxf(v, 0.f);
          size_t yi = (size_t)(n + i) * OC + o;
          if (YOUT == 0) ((unsigned short*)Yp)[yi] = f2bf(v);
          else           ((float*)Yp)[yi] = v;
        }
      }
    }
  } else {
    #pragma unroll
    for (int mf = 0; mf < MF; ++mf)
      #pragma unroll
      for (int i = 0; i < 4; ++i) {
        int o = o0 + wa * 32 + mf * 16 + lg * 4 + i;
        float bias = Bv[o];
        #pragma unroll
        for (int nf = 0; nf < NF; ++nf) {
          int n = n0 + wb * 64 + nf * 16 + l15;
          float v = acc[mf][nf][i] + bias;
          int b = n >> 11, m = n & 2047;
          ((float*)Yp)[((size_t)b * 256 + o) * 8192 + out_off + m] = v;
        }
      }
  }
}

// ---------------------------------------------------------------------------
// Weights -> bf16 (+ wp2) + fused bias sums.
// wreg layout (elems): w1b:0 w2b:131072 wresb:196608 wqb:327680 wkb:344064
//   wvb:360448 wob:376832 wrb:442368 wa1b:704512 wa2b:770048 wp2b:835584
// bsum: [0,1024) = bo+br ; [1024,1280) = b2+bres
// ---------------------------------------------------------------------------
__global__ __launch_bounds__(256)
void wcvt_all_k(const float* __restrict__ w1, const float* __restrict__ w2,
                const float* __restrict__ wres, const float* __restrict__ wq,
                const float* __restrict__ wk, const float* __restrict__ wv,
                const float* __restrict__ wo, const float* __restrict__ wr,
                const float* __restrict__ wa1, const float* __restrict__ wa2,
                const float* __restrict__ wp2,
                const float* __restrict__ bo, const float* __restrict__ br,
                const float* __restrict__ b2, const float* __restrict__ bres,
                unsigned short* __restrict__ wreg, float* __restrict__ bsum)
{
  int i = blockIdx.x * 256 + threadIdx.x;
  if      (i < 131072) wreg[i] = f2bf(w1[i]);
  else if (i < 196608) wreg[i] = f2bf(w2[i - 131072]);
  else if (i < 327680) wreg[i] = f2bf(wres[i - 196608]);
  else if (i < 344064) wreg[i] = f2bf(wq[i - 327680]);
  else if (i < 360448) wreg[i] = f2bf(wk[i - 344064]);
  else if (i < 376832) wreg[i] = f2bf(wv[i - 360448]);
  else if (i < 442368) wreg[i] = f2bf(wo[i - 376832]);
  else if (i < 704512) wreg[i] = f2bf(wr[i - 442368]);
  else if (i < 770048) wreg[i] = f2bf(wa1[i - 704512]);
  else if (i < 835584) wreg[i] = f2bf(wa2[i - 770048]);
  else if (i < 839680) wreg[i] = f2bf(wp2[i - 835584]);
  else {
    int j = i - 839680;
    if (j < 1024)      bsum[j] = bo[j] + br[j];
    else if (j < 1280) bsum[j] = b2[j - 1024] + bres[j - 1024];
  }
}

// ---------------------------------------------------------------------------
// Transpose-convert (B,256,2048) fp32 -> point-major [n][256] bf16
// ---------------------------------------------------------------------------
__global__ __launch_bounds__(256)
void cvtT_k(const float* __restrict__ fq, const float* __restrict__ fk,
            unsigned short* __restrict__ xqb, unsigned short* __restrict__ xkb)
{
  const int t  = threadIdx.x;
  const int m0 = blockIdx.x * 64;
  const int c0 = blockIdx.y * 64;
  const int z  = blockIdx.z;
  const int b  = z >> 1;
  const float* src = (z & 1) ? fk : fq;
  unsigned short* dst = (z & 1) ? xkb : xqb;
  __shared__ unsigned short sT[64][68];
  #pragma unroll
  for (int it = 0; it < 16; ++it) {
    int idx = it * 256 + t;
    int c = idx >> 6, m = idx & 63;
    sT[m][c] = f2bf(src[((size_t)b * 256 + c0 + c) * 2048 + m0 + m]);
  }
  __syncthreads();
  #pragma unroll
  for (int it = 0; it < 8; ++it) {
    int idx = it * 256 + t;
    int n = idx >> 5, cw = idx & 31;
    unsigned int w = *reinterpret_cast<const unsigned int*>(&sT[n][cw * 2]);
    *reinterpret_cast<unsigned int*>(&dst[((size_t)b * 2048 + m0 + n) * 256 + c0 + cw * 2]) = w;
  }
}

// ---------------------------------------------------------------------------
// KNN + fused pos-MLP layer1: writes ids AND t1 = relu(wp1 . delta + bp1)
// t1: bf16 [col][64], col = global_n*16 + nb
// ---------------------------------------------------------------------------
__global__ __launch_bounds__(256)
void knn_k(const float* __restrict__ xyz, int* __restrict__ ids,
           const float* __restrict__ wp1, const float* __restrict__ bp1,
           unsigned short* __restrict__ t1)
{
  __shared__ float sx[2048], sy[2048], sz[2048], ss[2048];
  __shared__ float s_wp1[192], s_bp1[64];
  __shared__ int   s_qid[4][16];
  const int blk = blockIdx.x;
  const int b   = blk >> 7;
  const int mg  = blk & 127;
  const int t   = threadIdx.x;
  const float* xb = xyz + (size_t)b * 2048 * 3;
  for (int i = t; i < 2048; i += 256) {
    float x = xb[3 * i], y = xb[3 * i + 1], z = xb[3 * i + 2];
    sx[i] = x; sy[i] = y; sz[i] = z;
    ss[i] = x * x + y * y + z * z;
  }
  if (t < 192) s_wp1[t] = wp1[t];
  if (t < 64)  s_bp1[t] = bp1[t];
  __syncthreads();
  const int wave = t >> 6, lane = t & 63;
  for (int qi = 0; qi < 4; ++qi) {
    const int m = mg * 16 + wave * 4 + qi;
    const float xm = sx[m], ym = sy[m], zm = sz[m], sqm = ss[m];
    float d[32];
    #pragma unroll
    for (int j = 0; j < 32; ++j) {
      int nn = lane + 64 * j;
      d[j] = sqm + ss[nn] - 2.f * (sx[nn] * xm + sy[nn] * ym + sz[nn] * zm);
    }
    int* outp = ids + ((size_t)b * 2048 + m) * 16;
    for (int it = 0; it < 16; ++it) {
      float bd = 3.4e38f; int bn = 0x7fffffff;
      #pragma unroll
      for (int j = 0; j < 32; ++j) {
        int nn = lane + 64 * j;
        if (d[j] < bd) { bd = d[j]; bn = nn; }
      }
      #pragma unroll
      for (int off = 32; off > 0; off >>= 1) {
        float od = __shfl_xor(bd, off, 64);
        int   on = __shfl_xor(bn, off, 64);
        if (od < bd || (od == bd && on < bn)) { bd = od; bn = on; }
      }
      if ((bn & 63) == lane) {
        #pragma unroll
        for (int j = 0; j < 32; ++j) if (j == (bn >> 6)) d[j] = 3.4e38f;
      }
      if (lane == 0) { outp[it] = bn; s_qid[wave][it] = bn; }
    }
    // fused pos layer1: t1[col][ch] = relu(wp1 . (xyz[nb]-xyz[m]) + bp1)
    unsigned short* t1p = t1 + (((size_t)b * 2048 + m) * 16) * 64;
    float w0 = s_wp1[lane * 3 + 0], w1v = s_wp1[lane * 3 + 1], w2v = s_wp1[lane * 3 + 2];
    float bb = s_bp1[lane];
    #pragma unroll
    for (int nb = 0; nb < 16; ++nb) {
      int id = s_qid[wave][nb];
      float dx = sx[id] - xm, dy = sy[id] - ym, dz = sz[id] - zm;
      float v = fmaxf(w0 * dx + w1v * dy + w2v * dz + bb, 0.f);
      t1p[nb * 64 + lane] = f2bf(v);
    }
  }
}

// ---------------------------------------------------------------------------
// prep2: gather + assemble a0 = q - k_nbr + pos, vp = v_nbr + pos (bf16)
// posb is consumed and vpg written IN PLACE (same buffer, same index).
// ---------------------------------------------------------------------------
__global__ __launch_bounds__(256)
void prep2_k(const unsigned short* __restrict__ qb, const unsigned short* __restrict__ kb,
             const unsigned short* __restrict__ vb, const int* __restrict__ idsp,
             const unsigned short* __restrict__ posb,
             unsigned short* __restrict__ a0g, unsigned short* __restrict__ vpg)
{
  const int n = blockIdx.x;
  const int b = n >> 11;
  const int t = threadIdx.x;
  __shared__ int s_id[16];
  if (t < 16) s_id[t] = idsp[(size_t)n * 16 + t];
  __syncthreads();
  const int k  = t >> 4;
  const int c0 = (t & 15) * 4;
  const int nb = s_id[k];
  size_t colb = ((size_t)n * 16 + k) * 64 + c0;
  ushort4 q4 = *reinterpret_cast<const ushort4*>(qb + (size_t)n * 64 + c0);
  ushort4 k4 = *reinterpret_cast<const ushort4*>(kb + ((size_t)b * 2048 + nb) * 64 + c0);
  ushort4 v4 = *reinterpret_cast<const ushort4*>(vb + ((size_t)b * 2048 + nb) * 64 + c0);
  ushort4 p4 = *reinterpret_cast<const ushort4*>(posb + colb);
  float p0 = bf2f(p4.x), p1 = bf2f(p4.y), p2 = bf2f(p4.z), p3 = bf2f(p4.w);
  ushort4 av, wv;
  av.x = f2bf(bf2f(q4.x) - bf2f(k4.x) + p0);
  av.y = f2bf(bf2f(q4.y) - bf2f(k4.y) + p1);
  av.z = f2bf(bf2f(q4.z) - bf2f(k4.z) + p2);
  av.w = f2bf(bf2f(q4.w) - bf2f(k4.w) + p3);
  wv.x = f2bf(bf2f(v4.x) + p0);
  wv.y = f2bf(bf2f(v4.y) + p1);
  wv.z = f2bf(bf2f(v4.z) + p2);
  wv.w = f2bf(bf2f(v4.w) + p3);
  *reinterpret_cast<ushort4*>(a0g + colb) = av;
  *reinterpret_cast<ushort4*>(vpg + colb) = wv;
}

// ---------------------------------------------------------------------------
// MFMA attention (round-2 VERIFIED structure: layer1 A=a0, layer2 via LDS
// h-bounce, both 16x16x32). Delta vs verified: UP loop inside (a0 frags
// loaded once), grid (1024) instead of (1024, UP).
// ---------------------------------------------------------------------------
__global__ __launch_bounds__(256)
void attn_mfma_k(const unsigned short* __restrict__ a0g,
                 const unsigned short* __restrict__ vpg,
                 const unsigned short* __restrict__ w1bf,
                 const unsigned short* __restrict__ w2bf,
                 const float* __restrict__ ba1, const float* __restrict__ ba2,
                 unsigned short* __restrict__ fb)
{
  const int wid  = threadIdx.x >> 6;
  const int lane = threadIdx.x & 63;
  const int l15  = lane & 15;
  const int lg   = lane >> 4;
  const int m0   = blockIdx.x * 256 + wid * 64;

  __shared__ unsigned short hb_all[4][2560];
  unsigned short* hb = hb_all[wid];

  // a0 A-frags: col = m0+mf*16+l15, ch = kf*32+lg*8..+7  (loaded ONCE)
  bfrag afr[4][2];
  #pragma unroll
  for (int mf = 0; mf < 4; ++mf)
    #pragma unroll
    for (int kf = 0; kf < 2; ++kf)
      afr[mf][kf] = *reinterpret_cast<const bfrag*>(
          a0g + (size_t)(m0 + mf * 16 + l15) * 64 + kf * 32 + lg * 8);

  for (int up = 0; up < UP_; ++up) {
    const unsigned short* W1 = w1bf + up * 16384;
    const unsigned short* W2 = w2bf + up * 16384;
    const float* B1 = ba1 + up * 256;
    const float* B2 = ba2 + up * 64;

    ffrag acc2[4][4];
    #pragma unroll
    for (int mf = 0; mf < 4; ++mf)
      #pragma unroll
      for (int nf = 0; nf < 4; ++nf)
        acc2[mf][nf] = (ffrag){0.f, 0.f, 0.f, 0.f};

    for (int oc = 0; oc < 8; ++oc) {
      bfrag w1f[2][2];
      #pragma unroll
      for (int nf = 0; nf < 2; ++nf)
        #pragma unroll
        for (int kf = 0; kf < 2; ++kf)
          w1f[nf][kf] = *reinterpret_cast<const bfrag*>(
              W1 + (size_t)(oc * 32 + nf * 16 + l15) * 64 + kf * 32 + lg * 8);
      float b1v[2] = { B1[oc * 32 + l15], B1[oc * 32 + 16 + l15] };

      ffrag acc1[4][2];
      #pragma unroll
      for (int mf = 0; mf < 4; ++mf)
        #pragma unroll
        for (int nf = 0; nf < 2; ++nf)
          acc1[mf][nf] = (ffrag){0.f, 0.f, 0.f, 0.f};
      #pragma unroll
      for (int mf = 0; mf < 4; ++mf)
        #pragma unroll
        for (int nf = 0; nf < 2; ++nf)
          #pragma unroll
          for (int kf = 0; kf < 2; ++kf)
            acc1[mf][nf] = __builtin_amdgcn_mfma_f32_16x16x32_bf16(
                afr[mf][kf], w1f[nf][kf], acc1[mf][nf], 0, 0, 0);

      // relu + bias, write h (bf16) transposed into wave-local swizzled LDS
      #pragma unroll
      for (int mf = 0; mf < 4; ++mf)
        #pragma unroll
        for (int nf = 0; nf < 2; ++nf)
          #pragma unroll
          for (int i = 0; i < 4; ++i) {
            float v = fmaxf(acc1[mf][nf][i] + b1v[nf], 0.f);
            int r = mf * 16 + lg * 4 + i;     // local column index
            int o = nf * 16 + l15;            // o within chunk [0,32)
            hb[r * 40 + (((o >> 3) ^ (r & 3)) << 3) + (o & 7)] = f2bf(v);
          }

      // layer 2: A = h^T rows (k = o, 8 contiguous), B = W2^T
      bfrag w2f[4];
      #pragma unroll
      for (int nf = 0; nf < 4; ++nf)
        w2f[nf] = *reinterpret_cast<const bfrag*>(
            W2 + (size_t)(nf * 16 + l15) * 256 + oc * 32 + lg * 8);
      #pragma unroll
      for (int mf = 0; mf < 4; ++mf) {
        int r = mf * 16 + l15;
        bfrag hf = *reinterpret_cast<const bfrag*>(hb + r * 40 + ((lg ^ (r & 3)) << 3));
        #pragma unroll
        for (int nf = 0; nf < 4; ++nf)
          acc2[mf][nf] = __builtin_amdgcn_mfma_f32_16x16x32_bf16(
              hf, w2f[nf], acc2[mf][nf], 0, 0, 0);
      }
    }

    // epilogue: bias+scale, softmax over 16 neighbors, weighted vp sum
    #pragma unroll
    for (int mf = 0; mf < 4; ++mf) {
      float fsel = 0.f;
      #pragma unroll
      for (int nf = 0; nf < 4; ++nf) {
        float b2v = B2[nf * 16 + l15];
        float v[4];
        #pragma unroll
        for (int i = 0; i < 4; ++i) v[i] = (acc2[mf][nf][i] + b2v) * 0.125f;
        float mx = fmaxf(fmaxf(v[0], v[1]), fmaxf(v[2], v[3]));
        mx = fmaxf(mx, __shfl_xor(mx, 16, 64));
        mx = fmaxf(mx, __shfl_xor(mx, 32, 64));
        float e[4], s = 0.f;
        #pragma unroll
        for (int i = 0; i < 4; ++i) { e[i] = exp2f((v[i] - mx) * 1.44269504088896f); s += e[i]; }
        s += __shfl_xor(s, 16, 64);
        s += __shfl_xor(s, 32, 64);
        float inv = 1.f / s;
        float fp = 0.f;
        #pragma unroll
        for (int i = 0; i < 4; ++i) {
          int col = m0 + mf * 16 + lg * 4 + i;
          float vpv = bf2f(vpg[(size_t)col * 64 + nf * 16 + l15]);
          fp = fmaf(e[i] * inv, vpv, fp);
        }
        fp += __shfl_xor(fp, 16, 64);
        fp += __shfl_xor(fp, 32, 64);
        if (lg == nf) fsel = fp;
      }
      int pt = blockIdx.x * 16 + wid * 4 + mf;
      fb[((size_t)up * NPT + pt) * 64 + lane] = f2bf(fsel);
    }
  }
}

// ---------------------------------------------------------------------------
extern "C" void kernel_launch(void* const* d_in, const int* in_sizes, int n_in,
                              void* d_out, int out_size, void* d_ws, size_t ws_size,
                              hipStream_t stream)
{
  const float* fq   = (const float*)d_in[0];
  const float* fk   = (const float*)d_in[1];
  const float* xyz  = (const float*)d_in[2];
  const float* w1   = (const float*)d_in[3];
  const float* b1   = (const float*)d_in[4];
  const float* w2   = (const float*)d_in[5];
  const float* b2   = (const float*)d_in[6];
  const float* wres = (const float*)d_in[7];
  const float* bres = (const float*)d_in[8];
  const float* wq   = (const float*)d_in[9];
  const float* bq   = (const float*)d_in[10];
  const float* wk   = (const float*)d_in[11];
  const float* bk   = (const float*)d_in[12];
  const float* wv   = (const float*)d_in[13];
  const float* bv   = (const float*)d_in[14];
  const float* wp1  = (const float*)d_in[15];
  const float* bp1  = (const float*)d_in[16];
  const float* wp2  = (const float*)d_in[17];
  const float* bp2  = (const float*)d_in[18];
  const float* wa1  = (const float*)d_in[19];
  const float* ba1  = (const float*)d_in[20];
  const float* wa2  = (const float*)d_in[21];
  const float* ba2  = (const float*)d_in[22];
  const float* wo   = (const float*)d_in[23];
  const float* bo   = (const float*)d_in[24];
  const float* wr   = (const float*)d_in[25];
  const float* br   = (const float*)d_in[26];
  float* out = (float*)d_out;
  (void)in_sizes; (void)n_in; (void)out_size; (void)ws_size;

  unsigned short* u    = (unsigned short*)d_ws;
  unsigned short* wreg = u;                        //   839,680
  unsigned short* xqb  = wreg + 839680;            // 4,194,304
  unsigned short* xkb  = xqb  + 4194304;
  unsigned short* ftsb = xkb  + 4194304;
  unsigned short* h1b  = ftsb + 4194304;           // reused as fbb
  unsigned short* a0g  = h1b  + 4194304;           // 16,777,216 (aliases t1)
  unsigned short* vpg  = a0g  + 16777216;          // 16,777,216 (aliases posb)
  unsigned short* qb   = vpg  + 16777216;          // 1,048,576
  unsigned short* kb   = qb   + 1048576;
  unsigned short* vb   = kb   + 1048576;
  int*   ids  = (int*)(vb + 1048576);              // 262,144 ints
  float* bsum = (float*)(ids + 262144);            // 1,280 floats

  unsigned short* w1b   = wreg;
  unsigned short* w2b   = wreg + 131072;
  unsigned short* wresb = wreg + 196608;
  unsigned short* wqb   = wreg + 327680;
  unsigned short* wkb   = wreg + 344064;
  unsigned short* wvb   = wreg + 360448;
  unsigned short* wob   = wreg + 376832;
  unsigned short* wrb   = wreg + 442368;
  unsigned short* wa1b  = wreg + 704512;
  unsigned short* wa2b  = wreg + 770048;
  unsigned short* wp2b  = wreg + 835584;
  unsigned short* t1    = a0g;    // alias: t1 dead before a0g written
  unsigned short* posb  = vpg;    // alias: consumed in place by prep2
  unsigned short* fbb   = h1b;
  const int BIG = 1 << 30;

  dim3 blk(256);

  wcvt_all_k<<<dim3(3285), blk, 0, stream>>>(w1, w2, wres, wq, wk, wv, wo, wr,
                                             wa1, wa2, wp2, bo, br, b2, bres, wreg, bsum);
  cvtT_k<<<dim3(32, 4, 16), blk, 0, stream>>>(fq, fk, xqb, xkb);
  knn_k<<<dim3(1024), blk, 0, stream>>>(xyz, ids, wp1, bp1, t1);

  // h1 = relu(w1 @ [fq;fk] + b1)  -> bf16 [n][256]
  bgemm_k<0, true, false><<<dim3(128, 4), blk, 0, stream>>>(
      xqb, xkb, xkb, 256, BIG, 256, 256, 256,
      w1b, w1b, BIG, 512, 512, b1, h1b, 512, 256, 0);
  // ftsv = [w2|wres] @ [h1;fq;fk] + (b2+bres) -> bf16 [n][256]
  bgemm_k<0, false, false><<<dim3(128, 4), blk, 0, stream>>>(
      h1b, xqb, xkb, 256, 512, 256, 256, 256,
      w2b, wresb, 256, 256, 512, bsum + 1024, ftsb, 768, 256, 0);
  // q, k, v projections -> bf16 [n][64]
  bgemm_k<0, false, false><<<dim3(128, 1), blk, 0, stream>>>(
      xqb, xqb, xqb, BIG, BIG, 256, 256, 256,
      wqb, wqb, BIG, 256, 256, bq, qb, 256, 64, 0);
  bgemm_k<0, false, false><<<dim3(128, 1), blk, 0, stream>>>(
      xkb, xkb, xkb, BIG, BIG, 256, 256, 256,
      wkb, wkb, BIG, 256, 256, bk, kb, 256, 64, 0);
  bgemm_k<0, false, false><<<dim3(128, 1), blk, 0, stream>>>(
      ftsb, ftsb, ftsb, BIG, BIG, 256, 256, 256,
      wvb, wvb, BIG, 256, 256, bv, vb, 256, 64, 0);

  // pos = wp2 @ t1 + bp2  -> bf16 [col][64]   (N = 262144 cols)
  bgemm_k<0, false, false><<<dim3(2048, 1), blk, 0, stream>>>(
      t1, t1, t1, BIG, BIG, 64, 64, 64,
      wp2b, wp2b, BIG, 64, 64, bp2, posb, 64, 64, 0);

  prep2_k<<<dim3(NPT), blk, 0, stream>>>(qb, kb, vb, ids, posb, a0g, vpg);
  attn_mfma_k<<<dim3(1024), blk, 0, stream>>>(a0g, vpg, wa1b, wa2b, ba1, ba2, fbb);

  // out[:, :, i*2048:(i+1)*2048] = [wo_i|wr_i] @ [f_i; ftsv] + (bo_i+br_i)
  for (int i = 0; i < UP_; ++i) {
    bgemm_k<2, false, true><<<dim3(128, 4), blk, 0, stream>>>(
        fbb + (size_t)i * 1048576, ftsb, ftsb, 64, BIG, 64, 256, 256,
        wob + (size_t)i * 16384, wrb + (size_t)i * 65536, 64, 64, 256,
        bsum + i * 256, out, 320, 256, i * 2048);
  }
}

// Round 6
// 455.037 us; speedup vs baseline: 14.6479x; 1.1594x over previous
//
#include <hip/hip_runtime.h>
#include <hip/hip_bf16.h>

#define B_  8
#define D_  256
#define M_  2048
#define DT_ 64
#define KT_ 16
#define UP_ 4
#define NPT (B_ * M_)   // 16384 total points

typedef short bfrag __attribute__((ext_vector_type(8)));   // 8 bf16 (4 VGPRs)
typedef float ffrag __attribute__((ext_vector_type(4)));   // 4 fp32 acc

static __device__ inline unsigned short f2bf(float x) {
  unsigned int u = __float_as_uint(x);
  unsigned int r = (u + 0x7fffu + ((u >> 16) & 1u)) >> 16;   // RNE
  return (unsigned short)r;
}
static __device__ inline float bf2f(unsigned short u) {
  return __uint_as_float(((unsigned int)u) << 16);
}
static __device__ inline unsigned int cvtpk(float lo, float hi) {
  unsigned int r;
  asm("v_cvt_pk_bf16_f32 %0, %1, %2" : "=v"(r) : "v"(lo), "v"(hi));
  return r;
}

__device__ __forceinline__ void gload16(const unsigned short* g, unsigned short* l) {
  __builtin_amdgcn_global_load_lds(
      (const __attribute__((address_space(1))) unsigned int*)(const void*)g,
      (__attribute__((address_space(3))) unsigned int*)(void*)l, 16, 0, 0);
}

// ---------------------------------------------------------------------------
// bf16 MFMA GEMM. Tile: 128 n x 64 o x 64 k (verified round-2/3/5).
// blockIdx.z strides (azs on A0 only, wzs0/1, bzs, ozs) allow batching
// uniform-stride launches (out-proj over UP).
// ---------------------------------------------------------------------------
template<int YOUT, bool RELU, bool SWAP>
__global__ __launch_bounds__(256)
void bgemm_k(const unsigned short* __restrict__ A0, const unsigned short* __restrict__ A1,
             const unsigned short* __restrict__ A2, int ae1, int ae2,
             int lda0, int lda1, int lda2,
             const unsigned short* __restrict__ W0, const unsigned short* __restrict__ W1,
             int be1, int ldw0, int ldw1,
             const float* __restrict__ Bv, void* __restrict__ Yp,
             int IC, int OC, int out_off,
             int azs, int wzs0, int wzs1, int bzs, int ozs)
{
  __shared__ unsigned short sX[128 * 64];
  __shared__ unsigned short sW[64 * 64];
  const int z = blockIdx.z;
  A0 += (size_t)z * azs;
  W0 += (size_t)z * wzs0;
  W1 += (size_t)z * wzs1;
  Bv += (size_t)z * bzs;
  out_off += z * ozs;
  const int t    = threadIdx.x;
  const int lane = t & 63, wid = t >> 6;
  const int l15  = lane & 15, lg = lane >> 4;
  const int n0   = blockIdx.x * 128;
  const int o0   = blockIdx.y * 64;
  constexpr int MF = SWAP ? 2 : 4;
  constexpr int NF = SWAP ? 4 : 2;
  const int wa = wid & 1;
  const int wb = wid >> 1;

  ffrag acc[MF][NF];
  #pragma unroll
  for (int mf = 0; mf < MF; ++mf)
    #pragma unroll
    for (int nf = 0; nf < NF; ++nf)
      acc[mf][nf] = (ffrag){0.f, 0.f, 0.f, 0.f};

  for (int k0 = 0; k0 < IC; k0 += 64) {
    const unsigned short* Ap; int lda, ka;
    if (k0 < ae1)      { Ap = A0; lda = lda0; ka = 0;   }
    else if (k0 < ae2) { Ap = A1; lda = lda1; ka = ae1; }
    else               { Ap = A2; lda = lda2; ka = ae2; }
    const unsigned short* Wp; int ldw, kw;
    if (k0 < be1) { Wp = W0; ldw = ldw0; kw = 0;   }
    else          { Wp = W1; ldw = ldw1; kw = be1; }
    #pragma unroll
    for (int it = 0; it < 4; ++it) {
      int idx = it * 256 + t;
      int r = idx >> 3;
      int e = ((idx & 7) * 8) ^ ((r & 7) << 3);
      gload16(Ap + (size_t)(n0 + r) * lda + (k0 - ka) + e, sX + idx * 8);
    }
    #pragma unroll
    for (int it = 0; it < 2; ++it) {
      int idx = it * 256 + t;
      int r = idx >> 3;
      int e = ((idx & 7) * 8) ^ ((r & 7) << 3);
      gload16(Wp + (size_t)(o0 + r) * ldw + (k0 - kw) + e, sW + idx * 8);
    }
    __syncthreads();
    bfrag af[MF][2], bfr[NF][2];
    #pragma unroll
    for (int mf = 0; mf < MF; ++mf)
      #pragma unroll
      for (int kf = 0; kf < 2; ++kf) {
        int r = SWAP ? (wa * 32 + mf * 16 + l15) : (wa * 64 + mf * 16 + l15);
        int e = (kf * 32 + lg * 8) ^ ((r & 7) << 3);
        af[mf][kf] = *reinterpret_cast<const bfrag*>((SWAP ? sW : sX) + r * 64 + e);
      }
    #pragma unroll
    for (int nf = 0; nf < NF; ++nf)
      #pragma unroll
      for (int kf = 0; kf < 2; ++kf) {
        int r = SWAP ? (wb * 64 + nf * 16 + l15) : (wb * 32 + nf * 16 + l15);
        int e = (kf * 32 + lg * 8) ^ ((r & 7) << 3);
        bfr[nf][kf] = *reinterpret_cast<const bfrag*>((SWAP ? sX : sW) + r * 64 + e);
      }
    #pragma unroll
    for (int kf = 0; kf < 2; ++kf)
      #pragma unroll
      for (int mf = 0; mf < MF; ++mf)
        #pragma unroll
        for (int nf = 0; nf < NF; ++nf)
          acc[mf][nf] = __builtin_amdgcn_mfma_f32_16x16x32_bf16(
              af[mf][kf], bfr[nf][kf], acc[mf][nf], 0, 0, 0);
    __syncthreads();
  }

  if (!SWAP) {
    #pragma unroll
    for (int mf = 0; mf < MF; ++mf) {
      int n = n0 + wa * 64 + mf * 16 + lg * 4;
      #pragma unroll
      for (int nf = 0; nf < NF; ++nf) {
        int o = o0 + wb * 32 + nf * 16 + l15;
        float bias = Bv[o];
        #pragma unroll
        for (int i = 0; i < 4; ++i) {
          float v = acc[mf][nf][i] + bias;
          if (RELU) v = fmaxf(v, 0.f);
          size_t yi = (size_t)(n + i) * OC + o;
          if (YOUT == 0) ((unsigned short*)Yp)[yi] = f2bf(v);
          else           ((float*)Yp)[yi] = v;
        }
      }
    }
  } else {
    #pragma unroll
    for (int mf = 0; mf < MF; ++mf)
      #pragma unroll
      for (int i = 0; i < 4; ++i) {
        int o = o0 + wa * 32 + mf * 16 + lg * 4 + i;
        float bias = Bv[o];
        #pragma unroll
        for (int nf = 0; nf < NF; ++nf) {
          int n = n0 + wb * 64 + nf * 16 + l15;
          float v = acc[mf][nf][i] + bias;
          int b = n >> 11, m = n & 2047;
          ((float*)Yp)[((size_t)b * 256 + o) * 8192 + out_off + m] = v;
        }
      }
  }
}

// ---------------------------------------------------------------------------
// Weights -> bf16 (+ wp2) + fused bias sums.
// wreg layout (elems): w1b:0 w2b:131072 wresb:196608 wqb:327680 wkb:344064
//   wvb:360448 wob:376832 wrb:442368 wa1b:704512 wa2b:770048 wp2b:835584
// bsum: [0,1024) = bo+br ; [1024,1280) = b2+bres
// ---------------------------------------------------------------------------
__global__ __launch_bounds__(256)
void wcvt_all_k(const float* __restrict__ w1, const float* __restrict__ w2,
                const float* __restrict__ wres, const float* __restrict__ wq,
                const float* __restrict__ wk, const float* __restrict__ wv,
                const float* __restrict__ wo, const float* __restrict__ wr,
                const float* __restrict__ wa1, const float* __restrict__ wa2,
                const float* __restrict__ wp2,
                const float* __restrict__ bo, const float* __restrict__ br,
                const float* __restrict__ b2, const float* __restrict__ bres,
                unsigned short* __restrict__ wreg, float* __restrict__ bsum)
{
  int i = blockIdx.x * 256 + threadIdx.x;
  if      (i < 131072) wreg[i] = f2bf(w1[i]);
  else if (i < 196608) wreg[i] = f2bf(w2[i - 131072]);
  else if (i < 327680) wreg[i] = f2bf(wres[i - 196608]);
  else if (i < 344064) wreg[i] = f2bf(wq[i - 327680]);
  else if (i < 360448) wreg[i] = f2bf(wk[i - 344064]);
  else if (i < 376832) wreg[i] = f2bf(wv[i - 360448]);
  else if (i < 442368) wreg[i] = f2bf(wo[i - 376832]);
  else if (i < 704512) wreg[i] = f2bf(wr[i - 442368]);
  else if (i < 770048) wreg[i] = f2bf(wa1[i - 704512]);
  else if (i < 835584) wreg[i] = f2bf(wa2[i - 770048]);
  else if (i < 839680) wreg[i] = f2bf(wp2[i - 835584]);
  else {
    int j = i - 839680;
    if (j < 1024)      bsum[j] = bo[j] + br[j];
    else if (j < 1280) bsum[j] = b2[j - 1024] + bres[j - 1024];
  }
}

// ---------------------------------------------------------------------------
// Transpose-convert (B,256,2048) fp32 -> point-major [n][256] bf16
// ---------------------------------------------------------------------------
__global__ __launch_bounds__(256)
void cvtT_k(const float* __restrict__ fq, const float* __restrict__ fk,
            unsigned short* __restrict__ xqb, unsigned short* __restrict__ xkb)
{
  const int t  = threadIdx.x;
  const int m0 = blockIdx.x * 64;
  const int c0 = blockIdx.y * 64;
  const int z  = blockIdx.z;
  const int b  = z >> 1;
  const float* src = (z & 1) ? fk : fq;
  unsigned short* dst = (z & 1) ? xkb : xqb;
  __shared__ unsigned short sT[64][68];
  #pragma unroll
  for (int it = 0; it < 16; ++it) {
    int idx = it * 256 + t;
    int c = idx >> 6, m = idx & 63;
    sT[m][c] = f2bf(src[((size_t)b * 256 + c0 + c) * 2048 + m0 + m]);
  }
  __syncthreads();
  #pragma unroll
  for (int it = 0; it < 8; ++it) {
    int idx = it * 256 + t;
    int n = idx >> 5, cw = idx & 31;
    unsigned int w = *reinterpret_cast<const unsigned int*>(&sT[n][cw * 2]);
    *reinterpret_cast<unsigned int*>(&dst[((size_t)b * 2048 + m0 + n) * 256 + c0 + cw * 2]) = w;
  }
}

// ---------------------------------------------------------------------------
// KNN + fused pos-MLP layer1: writes ids AND t1 = relu(wp1 . delta + bp1)
// ---------------------------------------------------------------------------
__global__ __launch_bounds__(256)
void knn_k(const float* __restrict__ xyz, int* __restrict__ ids,
           const float* __restrict__ wp1, const float* __restrict__ bp1,
           unsigned short* __restrict__ t1)
{
  __shared__ float sx[2048], sy[2048], sz[2048], ss[2048];
  __shared__ float s_wp1[192], s_bp1[64];
  __shared__ int   s_qid[4][16];
  const int blk = blockIdx.x;
  const int b   = blk >> 7;
  const int mg  = blk & 127;
  const int t   = threadIdx.x;
  const float* xb = xyz + (size_t)b * 2048 * 3;
  for (int i = t; i < 2048; i += 256) {
    float x = xb[3 * i], y = xb[3 * i + 1], z = xb[3 * i + 2];
    sx[i] = x; sy[i] = y; sz[i] = z;
    ss[i] = x * x + y * y + z * z;
  }
  if (t < 192) s_wp1[t] = wp1[t];
  if (t < 64)  s_bp1[t] = bp1[t];
  __syncthreads();
  const int wave = t >> 6, lane = t & 63;
  for (int qi = 0; qi < 4; ++qi) {
    const int m = mg * 16 + wave * 4 + qi;
    const float xm = sx[m], ym = sy[m], zm = sz[m], sqm = ss[m];
    float d[32];
    #pragma unroll
    for (int j = 0; j < 32; ++j) {
      int nn = lane + 64 * j;
      d[j] = sqm + ss[nn] - 2.f * (sx[nn] * xm + sy[nn] * ym + sz[nn] * zm);
    }
    int* outp = ids + ((size_t)b * 2048 + m) * 16;
    for (int it = 0; it < 16; ++it) {
      float bd = 3.4e38f; int bn = 0x7fffffff;
      #pragma unroll
      for (int j = 0; j < 32; ++j) {
        int nn = lane + 64 * j;
        if (d[j] < bd) { bd = d[j]; bn = nn; }
      }
      #pragma unroll
      for (int off = 32; off > 0; off >>= 1) {
        float od = __shfl_xor(bd, off, 64);
        int   on = __shfl_xor(bn, off, 64);
        if (od < bd || (od == bd && on < bn)) { bd = od; bn = on; }
      }
      if ((bn & 63) == lane) {
        #pragma unroll
        for (int j = 0; j < 32; ++j) if (j == (bn >> 6)) d[j] = 3.4e38f;
      }
      if (lane == 0) { outp[it] = bn; s_qid[wave][it] = bn; }
    }
    unsigned short* t1p = t1 + (((size_t)b * 2048 + m) * 16) * 64;
    float w0 = s_wp1[lane * 3 + 0], w1v = s_wp1[lane * 3 + 1], w2v = s_wp1[lane * 3 + 2];
    float bb = s_bp1[lane];
    #pragma unroll
    for (int nb = 0; nb < 16; ++nb) {
      int id = s_qid[wave][nb];
      float dx = sx[id] - xm, dy = sy[id] - ym, dz = sz[id] - zm;
      float v = fmaxf(w0 * dx + w1v * dy + w2v * dz + bb, 0.f);
      t1p[nb * 64 + lane] = f2bf(v);
    }
  }
}

// ---------------------------------------------------------------------------
// prep2: gather + assemble a0 = q - k_nbr + pos, vp = v_nbr + pos (bf16)
// ---------------------------------------------------------------------------
__global__ __launch_bounds__(256)
void prep2_k(const unsigned short* __restrict__ qb, const unsigned short* __restrict__ kb,
             const unsigned short* __restrict__ vb, const int* __restrict__ idsp,
             const unsigned short* __restrict__ posb,
             unsigned short* __restrict__ a0g, unsigned short* __restrict__ vpg)
{
  const int n = blockIdx.x;
  const int b = n >> 11;
  const int t = threadIdx.x;
  __shared__ int s_id[16];
  if (t < 16) s_id[t] = idsp[(size_t)n * 16 + t];
  __syncthreads();
  const int k  = t >> 4;
  const int c0 = (t & 15) * 4;
  const int nb = s_id[k];
  size_t colb = ((size_t)n * 16 + k) * 64 + c0;
  ushort4 q4 = *reinterpret_cast<const ushort4*>(qb + (size_t)n * 64 + c0);
  ushort4 k4 = *reinterpret_cast<const ushort4*>(kb + ((size_t)b * 2048 + nb) * 64 + c0);
  ushort4 v4 = *reinterpret_cast<const ushort4*>(vb + ((size_t)b * 2048 + nb) * 64 + c0);
  ushort4 p4 = *reinterpret_cast<const ushort4*>(posb + colb);
  float p0 = bf2f(p4.x), p1 = bf2f(p4.y), p2 = bf2f(p4.z), p3 = bf2f(p4.w);
  ushort4 av, wv;
  av.x = f2bf(bf2f(q4.x) - bf2f(k4.x) + p0);
  av.y = f2bf(bf2f(q4.y) - bf2f(k4.y) + p1);
  av.z = f2bf(bf2f(q4.z) - bf2f(k4.z) + p2);
  av.w = f2bf(bf2f(q4.w) - bf2f(k4.w) + p3);
  wv.x = f2bf(bf2f(v4.x) + p0);
  wv.y = f2bf(bf2f(v4.y) + p1);
  wv.z = f2bf(bf2f(v4.z) + p2);
  wv.w = f2bf(bf2f(v4.w) + p3);
  *reinterpret_cast<ushort4*>(a0g + colb) = av;
  *reinterpret_cast<ushort4*>(vpg + colb) = wv;
}

// ---------------------------------------------------------------------------
// MFMA attention (round-2 VERIFIED structure: grid (1024, UP), layer1 A=a0,
// layer2 via LDS h-bounce, both 16x16x32). Delta vs verified: h-bounce
// conversion uses HW v_cvt_pk_bf16_f32 (same RNE bits, 1/8 the VALU ops);
// addresses unchanged.
// ---------------------------------------------------------------------------
__global__ __launch_bounds__(256)
void attn_mfma_k(const unsigned short* __restrict__ a0g,
                 const unsigned short* __restrict__ vpg,
                 const unsigned short* __restrict__ w1bf,
                 const unsigned short* __restrict__ w2bf,
                 const float* __restrict__ ba1, const float* __restrict__ ba2,
                 unsigned short* __restrict__ fb)
{
  const int up   = blockIdx.y;
  const int wid  = threadIdx.x >> 6;
  const int lane = threadIdx.x & 63;
  const int l15  = lane & 15;
  const int lg   = lane >> 4;
  const int m0   = blockIdx.x * 256 + wid * 64;

  __shared__ unsigned short hb_all[4][2560];
  unsigned short* hb = hb_all[wid];

  const unsigned short* W1 = w1bf + up * 16384;
  const unsigned short* W2 = w2bf + up * 16384;
  const float* B1 = ba1 + up * 256;
  const float* B2 = ba2 + up * 64;

  bfrag afr[4][2];
  #pragma unroll
  for (int mf = 0; mf < 4; ++mf)
    #pragma unroll
    for (int kf = 0; kf < 2; ++kf)
      afr[mf][kf] = *reinterpret_cast<const bfrag*>(
          a0g + (size_t)(m0 + mf * 16 + l15) * 64 + kf * 32 + lg * 8);

  ffrag acc2[4][4];
  #pragma unroll
  for (int mf = 0; mf < 4; ++mf)
    #pragma unroll
    for (int nf = 0; nf < 4; ++nf)
      acc2[mf][nf] = (ffrag){0.f, 0.f, 0.f, 0.f};

  for (int oc = 0; oc < 8; ++oc) {
    bfrag w1f[2][2];
    #pragma unroll
    for (int nf = 0; nf < 2; ++nf)
      #pragma unroll
      for (int kf = 0; kf < 2; ++kf)
        w1f[nf][kf] = *reinterpret_cast<const bfrag*>(
            W1 + (size_t)(oc * 32 + nf * 16 + l15) * 64 + kf * 32 + lg * 8);
    float b1v[2] = { B1[oc * 32 + l15], B1[oc * 32 + 16 + l15] };

    ffrag acc1[4][2];
    #pragma unroll
    for (int mf = 0; mf < 4; ++mf)
      #pragma unroll
      for (int nf = 0; nf < 2; ++nf)
        acc1[mf][nf] = (ffrag){0.f, 0.f, 0.f, 0.f};
    #pragma unroll
    for (int mf = 0; mf < 4; ++mf)
      #pragma unroll
      for (int nf = 0; nf < 2; ++nf)
        #pragma unroll
        for (int kf = 0; kf < 2; ++kf)
          acc1[mf][nf] = __builtin_amdgcn_mfma_f32_16x16x32_bf16(
              afr[mf][kf], w1f[nf][kf], acc1[mf][nf], 0, 0, 0);

    // relu + bias, pack pairs with HW cvt_pk, write h transposed into LDS
    #pragma unroll
    for (int mf = 0; mf < 4; ++mf)
      #pragma unroll
      for (int nf = 0; nf < 2; ++nf) {
        int o = nf * 16 + l15;
        float vv[4];
        #pragma unroll
        for (int i = 0; i < 4; ++i) vv[i] = fmaxf(acc1[mf][nf][i] + b1v[nf], 0.f);
        #pragma unroll
        for (int p = 0; p < 2; ++p) {
          unsigned int d = cvtpk(vv[2 * p], vv[2 * p + 1]);
          int r0 = mf * 16 + lg * 4 + 2 * p;
          int r1 = r0 + 1;
          hb[r0 * 40 + (((o >> 3) ^ (r0 & 3)) << 3) + (o & 7)] = (unsigned short)d;
          hb[r1 * 40 + (((o >> 3) ^ (r1 & 3)) << 3) + (o & 7)] = (unsigned short)(d >> 16);
        }
      }

    // layer 2: A = h^T rows (k = o, 8 contiguous), B = W2^T
    bfrag w2f[4];
    #pragma unroll
    for (int nf = 0; nf < 4; ++nf)
      w2f[nf] = *reinterpret_cast<const bfrag*>(
          W2 + (size_t)(nf * 16 + l15) * 256 + oc * 32 + lg * 8);
    #pragma unroll
    for (int mf = 0; mf < 4; ++mf) {
      int r = mf * 16 + l15;
      bfrag hf = *reinterpret_cast<const bfrag*>(hb + r * 40 + ((lg ^ (r & 3)) << 3));
      #pragma unroll
      for (int nf = 0; nf < 4; ++nf)
        acc2[mf][nf] = __builtin_amdgcn_mfma_f32_16x16x32_bf16(
            hf, w2f[nf], acc2[mf][nf], 0, 0, 0);
    }
  }

  // epilogue: bias+scale, softmax over 16 neighbors, weighted vp sum
  #pragma unroll
  for (int mf = 0; mf < 4; ++mf) {
    float fsel = 0.f;
    #pragma unroll
    for (int nf = 0; nf < 4; ++nf) {
      float b2v = B2[nf * 16 + l15];
      float v[4];
      #pragma unroll
      for (int i = 0; i < 4; ++i) v[i] = (acc2[mf][nf][i] + b2v) * 0.125f;
      float mx = fmaxf(fmaxf(v[0], v[1]), fmaxf(v[2], v[3]));
      mx = fmaxf(mx, __shfl_xor(mx, 16, 64));
      mx = fmaxf(mx, __shfl_xor(mx, 32, 64));
      float e[4], s = 0.f;
      #pragma unroll
      for (int i = 0; i < 4; ++i) { e[i] = exp2f((v[i] - mx) * 1.44269504088896f); s += e[i]; }
      s += __shfl_xor(s, 16, 64);
      s += __shfl_xor(s, 32, 64);
      float inv = 1.f / s;
      float fp = 0.f;
      #pragma unroll
      for (int i = 0; i < 4; ++i) {
        int col = m0 + mf * 16 + lg * 4 + i;
        float vpv = bf2f(vpg[(size_t)col * 64 + nf * 16 + l15]);
        fp = fmaf(e[i] * inv, vpv, fp);
      }
      fp += __shfl_xor(fp, 16, 64);
      fp += __shfl_xor(fp, 32, 64);
      if (lg == nf) fsel = fp;
    }
    int pt = blockIdx.x * 16 + wid * 4 + mf;
    fb[((size_t)up * NPT + pt) * 64 + lane] = f2bf(fsel);
  }
}

// ---------------------------------------------------------------------------
extern "C" void kernel_launch(void* const* d_in, const int* in_sizes, int n_in,
                              void* d_out, int out_size, void* d_ws, size_t ws_size,
                              hipStream_t stream)
{
  const float* fq   = (const float*)d_in[0];
  const float* fk   = (const float*)d_in[1];
  const float* xyz  = (const float*)d_in[2];
  const float* w1   = (const float*)d_in[3];
  const float* b1   = (const float*)d_in[4];
  const float* w2   = (const float*)d_in[5];
  const float* b2   = (const float*)d_in[6];
  const float* wres = (const float*)d_in[7];
  const float* bres = (const float*)d_in[8];
  const float* wq   = (const float*)d_in[9];
  const float* bq   = (const float*)d_in[10];
  const float* wk   = (const float*)d_in[11];
  const float* bk   = (const float*)d_in[12];
  const float* wv   = (const float*)d_in[13];
  const float* bv   = (const float*)d_in[14];
  const float* wp1  = (const float*)d_in[15];
  const float* bp1  = (const float*)d_in[16];
  const float* wp2  = (const float*)d_in[17];
  const float* bp2  = (const float*)d_in[18];
  const float* wa1  = (const float*)d_in[19];
  const float* ba1  = (const float*)d_in[20];
  const float* wa2  = (const float*)d_in[21];
  const float* ba2  = (const float*)d_in[22];
  const float* wo   = (const float*)d_in[23];
  const float* bo   = (const float*)d_in[24];
  const float* wr   = (const float*)d_in[25];
  const float* br   = (const float*)d_in[26];
  float* out = (float*)d_out;
  (void)in_sizes; (void)n_in; (void)out_size; (void)ws_size;

  unsigned short* u    = (unsigned short*)d_ws;
  unsigned short* wreg = u;                        //   839,680
  unsigned short* xqb  = wreg + 839680;            // 4,194,304
  unsigned short* xkb  = xqb  + 4194304;
  unsigned short* ftsb = xkb  + 4194304;
  unsigned short* h1b  = ftsb + 4194304;           // reused as fbb
  unsigned short* a0g  = h1b  + 4194304;           // 16,777,216 (aliases t1)
  unsigned short* vpg  = a0g  + 16777216;          // 16,777,216 (aliases posb)
  unsigned short* qb   = vpg  + 16777216;          // 1,048,576
  unsigned short* kb   = qb   + 1048576;
  unsigned short* vb   = kb   + 1048576;
  int*   ids  = (int*)(vb + 1048576);              // 262,144 ints
  float* bsum = (float*)(ids + 262144);            // 1,280 floats

  unsigned short* w1b   = wreg;
  unsigned short* w2b   = wreg + 131072;
  unsigned short* wresb = wreg + 196608;
  unsigned short* wqb   = wreg + 327680;
  unsigned short* wkb   = wreg + 344064;
  unsigned short* wvb   = wreg + 360448;
  unsigned short* wob   = wreg + 376832;
  unsigned short* wrb   = wreg + 442368;
  unsigned short* wa1b  = wreg + 704512;
  unsigned short* wa2b  = wreg + 770048;
  unsigned short* wp2b  = wreg + 835584;
  unsigned short* t1    = a0g;    // alias: t1 dead before a0g written
  unsigned short* posb  = vpg;    // alias: consumed in place by prep2
  unsigned short* fbb   = h1b;
  const int BIG = 1 << 30;

  dim3 blk(256);

  wcvt_all_k<<<dim3(3285), blk, 0, stream>>>(w1, w2, wres, wq, wk, wv, wo, wr,
                                             wa1, wa2, wp2, bo, br, b2, bres, wreg, bsum);
  cvtT_k<<<dim3(32, 4, 16), blk, 0, stream>>>(fq, fk, xqb, xkb);
  knn_k<<<dim3(1024), blk, 0, stream>>>(xyz, ids, wp1, bp1, t1);

  // h1 = relu(w1 @ [fq;fk] + b1)  -> bf16 [n][256]
  bgemm_k<0, true, false><<<dim3(128, 4), blk, 0, stream>>>(
      xqb, xkb, xkb, 256, BIG, 256, 256, 256,
      w1b, w1b, BIG, 512, 512, b1, h1b, 512, 256, 0, 0, 0, 0, 0, 0);
  // ftsv = [w2|wres] @ [h1;fq;fk] + (b2+bres) -> bf16 [n][256]
  bgemm_k<0, false, false><<<dim3(128, 4), blk, 0, stream>>>(
      h1b, xqb, xkb, 256, 512, 256, 256, 256,
      w2b, wresb, 256, 256, 512, bsum + 1024, ftsb, 768, 256, 0, 0, 0, 0, 0, 0);
  // q, k, v projections -> bf16 [n][64]
  bgemm_k<0, false, false><<<dim3(128, 1), blk, 0, stream>>>(
      xqb, xqb, xqb, BIG, BIG, 256, 256, 256,
      wqb, wqb, BIG, 256, 256, bq, qb, 256, 64, 0, 0, 0, 0, 0, 0);
  bgemm_k<0, false, false><<<dim3(128, 1), blk, 0, stream>>>(
      xkb, xkb, xkb, BIG, BIG, 256, 256, 256,
      wkb, wkb, BIG, 256, 256, bk, kb, 256, 64, 0, 0, 0, 0, 0, 0);
  bgemm_k<0, false, false><<<dim3(128, 1), blk, 0, stream>>>(
      ftsb, ftsb, ftsb, BIG, BIG, 256, 256, 256,
      wvb, wvb, BIG, 256, 256, bv, vb, 256, 64, 0, 0, 0, 0, 0, 0);

  // pos = wp2 @ t1 + bp2  -> bf16 [col][64]   (N = 262144 cols)
  bgemm_k<0, false, false><<<dim3(2048, 1), blk, 0, stream>>>(
      t1, t1, t1, BIG, BIG, 64, 64, 64,
      wp2b, wp2b, BIG, 64, 64, bp2, posb, 64, 64, 0, 0, 0, 0, 0, 0);

  prep2_k<<<dim3(NPT), blk, 0, stream>>>(qb, kb, vb, ids, posb, a0g, vpg);
  attn_mfma_k<<<dim3(1024, UP_), blk, 0, stream>>>(a0g, vpg, wa1b, wa2b, ba1, ba2, fbb);

  // out[:, :, i*2048:(i+1)*2048] = [wo_i|wr_i] @ [f_i; ftsv] + (bo_i+br_i)
  // single launch, blockIdx.z = up (uniform strides)
  bgemm_k<2, false, true><<<dim3(128, 4, UP_), blk, 0, stream>>>(
      fbb, ftsb, ftsb, 64, BIG, 64, 256, 256,
      wob, wrb, 64, 64, 256,
      bsum, out, 320, 256, 0,
      1048576, 16384, 65536, 256, 2048);
}

// Round 7
// 444.613 us; speedup vs baseline: 14.9913x; 1.0234x over previous
//
#include <hip/hip_runtime.h>
#include <hip/hip_bf16.h>

#define B_  8
#define D_  256
#define M_  2048
#define DT_ 64
#define KT_ 16
#define UP_ 4
#define NPT (B_ * M_)   // 16384 total points

typedef short bfrag __attribute__((ext_vector_type(8)));   // 8 bf16 (4 VGPRs)
typedef float ffrag __attribute__((ext_vector_type(4)));   // 4 fp32 acc

static __device__ inline unsigned short f2bf(float x) {
  unsigned int u = __float_as_uint(x);
  unsigned int r = (u + 0x7fffu + ((u >> 16) & 1u)) >> 16;   // RNE
  return (unsigned short)r;
}
static __device__ inline float bf2f(unsigned short u) {
  return __uint_as_float(((unsigned int)u) << 16);
}
static __device__ inline unsigned int cvtpk(float lo, float hi) {
  unsigned int r;
  asm("v_cvt_pk_bf16_f32 %0, %1, %2" : "=v"(r) : "v"(lo), "v"(hi));
  return r;
}

__device__ __forceinline__ void gload16(const unsigned short* g, unsigned short* l) {
  __builtin_amdgcn_global_load_lds(
      (const __attribute__((address_space(1))) unsigned int*)(const void*)g,
      (__attribute__((address_space(3))) unsigned int*)(void*)l, 16, 0, 0);
}

// ---------------------------------------------------------------------------
// bf16 MFMA GEMM. Tile: 128 n x 64 o x 64 k (verified round-2/3/5/6).
// blockIdx.z strides (azs on A0, wzs0/1, bzs, ozs, yzs) batch uniform-stride
// launches (out-proj over UP; fused q/k/v).
// ---------------------------------------------------------------------------
template<int YOUT, bool RELU, bool SWAP>
__global__ __launch_bounds__(256)
void bgemm_k(const unsigned short* __restrict__ A0, const unsigned short* __restrict__ A1,
             const unsigned short* __restrict__ A2, int ae1, int ae2,
             int lda0, int lda1, int lda2,
             const unsigned short* __restrict__ W0, const unsigned short* __restrict__ W1,
             int be1, int ldw0, int ldw1,
             const float* __restrict__ Bv, void* __restrict__ Yp,
             int IC, int OC, int out_off,
             int azs, int wzs0, int wzs1, int bzs, int ozs, int yzs)
{
  __shared__ unsigned short sX[128 * 64];
  __shared__ unsigned short sW[64 * 64];
  const int z = blockIdx.z;
  A0 += (size_t)z * azs;
  W0 += (size_t)z * wzs0;
  W1 += (size_t)z * wzs1;
  Bv += (size_t)z * bzs;
  out_off += z * ozs;
  unsigned short* Yb = (unsigned short*)Yp + (size_t)z * yzs;
  float*          Yf = (float*)Yp + (size_t)z * yzs;
  const int t    = threadIdx.x;
  const int lane = t & 63, wid = t >> 6;
  const int l15  = lane & 15, lg = lane >> 4;
  const int n0   = blockIdx.x * 128;
  const int o0   = blockIdx.y * 64;
  constexpr int MF = SWAP ? 2 : 4;
  constexpr int NF = SWAP ? 4 : 2;
  const int wa = wid & 1;
  const int wb = wid >> 1;

  ffrag acc[MF][NF];
  #pragma unroll
  for (int mf = 0; mf < MF; ++mf)
    #pragma unroll
    for (int nf = 0; nf < NF; ++nf)
      acc[mf][nf] = (ffrag){0.f, 0.f, 0.f, 0.f};

  for (int k0 = 0; k0 < IC; k0 += 64) {
    const unsigned short* Ap; int lda, ka;
    if (k0 < ae1)      { Ap = A0; lda = lda0; ka = 0;   }
    else if (k0 < ae2) { Ap = A1; lda = lda1; ka = ae1; }
    else               { Ap = A2; lda = lda2; ka = ae2; }
    const unsigned short* Wp; int ldw, kw;
    if (k0 < be1) { Wp = W0; ldw = ldw0; kw = 0;   }
    else          { Wp = W1; ldw = ldw1; kw = be1; }
    #pragma unroll
    for (int it = 0; it < 4; ++it) {
      int idx = it * 256 + t;
      int r = idx >> 3;
      int e = ((idx & 7) * 8) ^ ((r & 7) << 3);
      gload16(Ap + (size_t)(n0 + r) * lda + (k0 - ka) + e, sX + idx * 8);
    }
    #pragma unroll
    for (int it = 0; it < 2; ++it) {
      int idx = it * 256 + t;
      int r = idx >> 3;
      int e = ((idx & 7) * 8) ^ ((r & 7) << 3);
      gload16(Wp + (size_t)(o0 + r) * ldw + (k0 - kw) + e, sW + idx * 8);
    }
    __syncthreads();
    bfrag af[MF][2], bfr[NF][2];
    #pragma unroll
    for (int mf = 0; mf < MF; ++mf)
      #pragma unroll
      for (int kf = 0; kf < 2; ++kf) {
        int r = SWAP ? (wa * 32 + mf * 16 + l15) : (wa * 64 + mf * 16 + l15);
        int e = (kf * 32 + lg * 8) ^ ((r & 7) << 3);
        af[mf][kf] = *reinterpret_cast<const bfrag*>((SWAP ? sW : sX) + r * 64 + e);
      }
    #pragma unroll
    for (int nf = 0; nf < NF; ++nf)
      #pragma unroll
      for (int kf = 0; kf < 2; ++kf) {
        int r = SWAP ? (wb * 64 + nf * 16 + l15) : (wb * 32 + nf * 16 + l15);
        int e = (kf * 32 + lg * 8) ^ ((r & 7) << 3);
        bfr[nf][kf] = *reinterpret_cast<const bfrag*>((SWAP ? sX : sW) + r * 64 + e);
      }
    #pragma unroll
    for (int kf = 0; kf < 2; ++kf)
      #pragma unroll
      for (int mf = 0; mf < MF; ++mf)
        #pragma unroll
        for (int nf = 0; nf < NF; ++nf)
          acc[mf][nf] = __builtin_amdgcn_mfma_f32_16x16x32_bf16(
              af[mf][kf], bfr[nf][kf], acc[mf][nf], 0, 0, 0);
    __syncthreads();
  }

  if (!SWAP) {
    #pragma unroll
    for (int mf = 0; mf < MF; ++mf) {
      int n = n0 + wa * 64 + mf * 16 + lg * 4;
      #pragma unroll
      for (int nf = 0; nf < NF; ++nf) {
        int o = o0 + wb * 32 + nf * 16 + l15;
        float bias = Bv[o];
        #pragma unroll
        for (int i = 0; i < 4; ++i) {
          float v = acc[mf][nf][i] + bias;
          if (RELU) v = fmaxf(v, 0.f);
          size_t yi = (size_t)(n + i) * OC + o;
          if (YOUT == 0) Yb[yi] = f2bf(v);
          else           Yf[yi] = v;
        }
      }
    }
  } else {
    #pragma unroll
    for (int mf = 0; mf < MF; ++mf)
      #pragma unroll
      for (int i = 0; i < 4; ++i) {
        int o = o0 + wa * 32 + mf * 16 + lg * 4 + i;
        float bias = Bv[o];
        #pragma unroll
        for (int nf = 0; nf < NF; ++nf) {
          int n = n0 + wb * 64 + nf * 16 + l15;
          float v = acc[mf][nf][i] + bias;
          int b = n >> 11, m = n & 2047;
          Yf[((size_t)b * 256 + o) * 8192 + out_off + m] = v;
        }
      }
  }
}

// ---------------------------------------------------------------------------
// Weights -> bf16 (+ wp2) + fused bias sums + bq/bk/bv copies.
// wreg layout (elems): w1b:0 w2b:131072 wresb:196608 wqb:327680 wkb:344064
//   wvb:360448 wob:376832 wrb:442368 wa1b:704512 wa2b:770048 wp2b:835584
// bsum: [0,1024)=bo+br ; [1024,1280)=b2+bres ; [1280,1472)=bq|bk|bv
// ---------------------------------------------------------------------------
__global__ __launch_bounds__(256)
void wcvt_all_k(const float* __restrict__ w1, const float* __restrict__ w2,
                const float* __restrict__ wres, const float* __restrict__ wq,
                const float* __restrict__ wk, const float* __restrict__ wv,
                const float* __restrict__ wo, const float* __restrict__ wr,
                const float* __restrict__ wa1, const float* __restrict__ wa2,
                const float* __restrict__ wp2,
                const float* __restrict__ bo, const float* __restrict__ br,
                const float* __restrict__ b2, const float* __restrict__ bres,
                const float* __restrict__ bq, const float* __restrict__ bk,
                const float* __restrict__ bv,
                unsigned short* __restrict__ wreg, float* __restrict__ bsum)
{
  int i = blockIdx.x * 256 + threadIdx.x;
  if      (i < 131072) wreg[i] = f2bf(w1[i]);
  else if (i < 196608) wreg[i] = f2bf(w2[i - 131072]);
  else if (i < 327680) wreg[i] = f2bf(wres[i - 196608]);
  else if (i < 344064) wreg[i] = f2bf(wq[i - 327680]);
  else if (i < 360448) wreg[i] = f2bf(wk[i - 344064]);
  else if (i < 376832) wreg[i] = f2bf(wv[i - 360448]);
  else if (i < 442368) wreg[i] = f2bf(wo[i - 376832]);
  else if (i < 704512) wreg[i] = f2bf(wr[i - 442368]);
  else if (i < 770048) wreg[i] = f2bf(wa1[i - 704512]);
  else if (i < 835584) wreg[i] = f2bf(wa2[i - 770048]);
  else if (i < 839680) wreg[i] = f2bf(wp2[i - 835584]);
  else {
    int j = i - 839680;
    if (j < 1024)      bsum[j] = bo[j] + br[j];
    else if (j < 1280) bsum[j] = b2[j - 1024] + bres[j - 1024];
    else if (j < 1472) {
      int j2 = j - 1280, zz = j2 >> 6, o = j2 & 63;
      bsum[j] = (zz == 0) ? bq[o] : (zz == 1) ? bk[o] : bv[o];
    }
  }
}

// ---------------------------------------------------------------------------
// Transpose-convert (B,256,2048) fp32 -> point-major [n][256] bf16
// ---------------------------------------------------------------------------
__global__ __launch_bounds__(256)
void cvtT_k(const float* __restrict__ fq, const float* __restrict__ fk,
            unsigned short* __restrict__ xqb, unsigned short* __restrict__ xkb)
{
  const int t  = threadIdx.x;
  const int m0 = blockIdx.x * 64;
  const int c0 = blockIdx.y * 64;
  const int z  = blockIdx.z;
  const int b  = z >> 1;
  const float* src = (z & 1) ? fk : fq;
  unsigned short* dst = (z & 1) ? xkb : xqb;
  __shared__ unsigned short sT[64][68];
  #pragma unroll
  for (int it = 0; it < 16; ++it) {
    int idx = it * 256 + t;
    int c = idx >> 6, m = idx & 63;
    sT[m][c] = f2bf(src[((size_t)b * 256 + c0 + c) * 2048 + m0 + m]);
  }
  __syncthreads();
  #pragma unroll
  for (int it = 0; it < 8; ++it) {
    int idx = it * 256 + t;
    int n = idx >> 5, cw = idx & 31;
    unsigned int w = *reinterpret_cast<const unsigned int*>(&sT[n][cw * 2]);
    *reinterpret_cast<unsigned int*>(&dst[((size_t)b * 2048 + m0 + n) * 256 + c0 + cw * 2]) = w;
  }
}

// ---------------------------------------------------------------------------
// KNN + fused pos-MLP layer1: writes ids AND t1 = relu(wp1 . delta + bp1)
// ---------------------------------------------------------------------------
__global__ __launch_bounds__(256)
void knn_k(const float* __restrict__ xyz, int* __restrict__ ids,
           const float* __restrict__ wp1, const float* __restrict__ bp1,
           unsigned short* __restrict__ t1)
{
  __shared__ float sx[2048], sy[2048], sz[2048], ss[2048];
  __shared__ float s_wp1[192], s_bp1[64];
  __shared__ int   s_qid[4][16];
  const int blk = blockIdx.x;
  const int b   = blk >> 7;
  const int mg  = blk & 127;
  const int t   = threadIdx.x;
  const float* xb = xyz + (size_t)b * 2048 * 3;
  for (int i = t; i < 2048; i += 256) {
    float x = xb[3 * i], y = xb[3 * i + 1], z = xb[3 * i + 2];
    sx[i] = x; sy[i] = y; sz[i] = z;
    ss[i] = x * x + y * y + z * z;
  }
  if (t < 192) s_wp1[t] = wp1[t];
  if (t < 64)  s_bp1[t] = bp1[t];
  __syncthreads();
  const int wave = t >> 6, lane = t & 63;
  for (int qi = 0; qi < 4; ++qi) {
    const int m = mg * 16 + wave * 4 + qi;
    const float xm = sx[m], ym = sy[m], zm = sz[m], sqm = ss[m];
    float d[32];
    #pragma unroll
    for (int j = 0; j < 32; ++j) {
      int nn = lane + 64 * j;
      d[j] = sqm + ss[nn] - 2.f * (sx[nn] * xm + sy[nn] * ym + sz[nn] * zm);
    }
    int* outp = ids + ((size_t)b * 2048 + m) * 16;
    for (int it = 0; it < 16; ++it) {
      float bd = 3.4e38f; int bn = 0x7fffffff;
      #pragma unroll
      for (int j = 0; j < 32; ++j) {
        int nn = lane + 64 * j;
        if (d[j] < bd) { bd = d[j]; bn = nn; }
      }
      #pragma unroll
      for (int off = 32; off > 0; off >>= 1) {
        float od = __shfl_xor(bd, off, 64);
        int   on = __shfl_xor(bn, off, 64);
        if (od < bd || (od == bd && on < bn)) { bd = od; bn = on; }
      }
      if ((bn & 63) == lane) {
        #pragma unroll
        for (int j = 0; j < 32; ++j) if (j == (bn >> 6)) d[j] = 3.4e38f;
      }
      if (lane == 0) { outp[it] = bn; s_qid[wave][it] = bn; }
    }
    unsigned short* t1p = t1 + (((size_t)b * 2048 + m) * 16) * 64;
    float w0 = s_wp1[lane * 3 + 0], w1v = s_wp1[lane * 3 + 1], w2v = s_wp1[lane * 3 + 2];
    float bb = s_bp1[lane];
    #pragma unroll
    for (int nb = 0; nb < 16; ++nb) {
      int id = s_qid[wave][nb];
      float dx = sx[id] - xm, dy = sy[id] - ym, dz = sz[id] - zm;
      float v = fmaxf(w0 * dx + w1v * dy + w2v * dz + bb, 0.f);
      t1p[nb * 64 + lane] = f2bf(v);
    }
  }
}

// ---------------------------------------------------------------------------
// prep2: gather + assemble a0 = q - k_nbr + pos, vp = v_nbr + pos (bf16)
// ---------------------------------------------------------------------------
__global__ __launch_bounds__(256)
void prep2_k(const unsigned short* __restrict__ qb, const unsigned short* __restrict__ kb,
             const unsigned short* __restrict__ vb, const int* __restrict__ idsp,
             const unsigned short* __restrict__ posb,
             unsigned short* __restrict__ a0g, unsigned short* __restrict__ vpg)
{
  const int n = blockIdx.x;
  const int b = n >> 11;
  const int t = threadIdx.x;
  __shared__ int s_id[16];
  if (t < 16) s_id[t] = idsp[(size_t)n * 16 + t];
  __syncthreads();
  const int k  = t >> 4;
  const int c0 = (t & 15) * 4;
  const int nb = s_id[k];
  size_t colb = ((size_t)n * 16 + k) * 64 + c0;
  ushort4 q4 = *reinterpret_cast<const ushort4*>(qb + (size_t)n * 64 + c0);
  ushort4 k4 = *reinterpret_cast<const ushort4*>(kb + ((size_t)b * 2048 + nb) * 64 + c0);
  ushort4 v4 = *reinterpret_cast<const ushort4*>(vb + ((size_t)b * 2048 + nb) * 64 + c0);
  ushort4 p4 = *reinterpret_cast<const ushort4*>(posb + colb);
  float p0 = bf2f(p4.x), p1 = bf2f(p4.y), p2 = bf2f(p4.z), p3 = bf2f(p4.w);
  ushort4 av, wv;
  av.x = f2bf(bf2f(q4.x) - bf2f(k4.x) + p0);
  av.y = f2bf(bf2f(q4.y) - bf2f(k4.y) + p1);
  av.z = f2bf(bf2f(q4.z) - bf2f(k4.z) + p2);
  av.w = f2bf(bf2f(q4.w) - bf2f(k4.w) + p3);
  wv.x = f2bf(bf2f(v4.x) + p0);
  wv.y = f2bf(bf2f(v4.y) + p1);
  wv.z = f2bf(bf2f(v4.z) + p2);
  wv.w = f2bf(bf2f(v4.w) + p3);
  *reinterpret_cast<ushort4*>(a0g + colb) = av;
  *reinterpret_cast<ushort4*>(vpg + colb) = wv;
}

// ---------------------------------------------------------------------------
// MFMA attention v3: ZERO LDS, zero barriers. Only verified 16x16x32 MFMA.
// layer1: A = W1 rows o-PERMUTED (o = oc*32 + 8*(l15>>2) + 4p + (l15&3)),
//         B = a0 frags. C: col(l15) = a0-col, row(lg*4+i) = o = 8lg+4p+i.
// => after cvt_pk pack, C IS the layer-2 A-fragment (k = lg*8 + (4p+i)).
// layer2: A = packed h, B = W2^T (k = o contiguous, same permuted order).
// C layout identical to round-6 verified epilogue (col=dt, row=a0col).
// ---------------------------------------------------------------------------
__global__ __launch_bounds__(256)
void attn_mfma_k(const unsigned short* __restrict__ a0g,
                 const unsigned short* __restrict__ vpg,
                 const unsigned short* __restrict__ w1bf,
                 const unsigned short* __restrict__ w2bf,
                 const float* __restrict__ ba1, const float* __restrict__ ba2,
                 unsigned short* __restrict__ fb)
{
  const int up   = blockIdx.y;
  const int wid  = threadIdx.x >> 6;
  const int lane = threadIdx.x & 63;
  const int l15  = lane & 15;
  const int lg   = lane >> 4;
  const int m0   = blockIdx.x * 256 + wid * 64;

  const unsigned short* W1 = w1bf + up * 16384;   // [o][ch], ch contiguous
  const unsigned short* W2 = w2bf + up * 16384;   // [dt][o], o contiguous
  const float* B1 = ba1 + up * 256;
  const float* B2 = ba2 + up * 64;

  // a0 B-frags: col = m0+nfc*16+l15, ch = kf*32+lg*8..+7 (loaded once)
  bfrag bf[4][2];
  #pragma unroll
  for (int nfc = 0; nfc < 4; ++nfc)
    #pragma unroll
    for (int kf = 0; kf < 2; ++kf)
      bf[nfc][kf] = *reinterpret_cast<const bfrag*>(
          a0g + (size_t)(m0 + nfc * 16 + l15) * 64 + kf * 32 + lg * 8);

  ffrag acc2[4][4];
  #pragma unroll
  for (int mf = 0; mf < 4; ++mf)
    #pragma unroll
    for (int nf = 0; nf < 4; ++nf)
      acc2[mf][nf] = (ffrag){0.f, 0.f, 0.f, 0.f};

  const int orow_base = ((l15 >> 2) << 3) + (l15 & 3);   // 8*(l15>>2)+(l15&3)

  for (int oc = 0; oc < 8; ++oc) {
    // layer1 A-frags: W1 row o = oc*32 + orow_base + 4p
    bfrag w1p[2][2];
    #pragma unroll
    for (int p = 0; p < 2; ++p)
      #pragma unroll
      for (int kf = 0; kf < 2; ++kf)
        w1p[p][kf] = *reinterpret_cast<const bfrag*>(
            W1 + (size_t)(oc * 32 + orow_base + 4 * p) * 64 + kf * 32 + lg * 8);
    float4 b1q[2];
    #pragma unroll
    for (int p = 0; p < 2; ++p)
      b1q[p] = *reinterpret_cast<const float4*>(B1 + oc * 32 + lg * 8 + 4 * p);

    ffrag acc1[2][4];
    #pragma unroll
    for (int p = 0; p < 2; ++p)
      #pragma unroll
      for (int nfc = 0; nfc < 4; ++nfc)
        acc1[p][nfc] = (ffrag){0.f, 0.f, 0.f, 0.f};
    #pragma unroll
    for (int kf = 0; kf < 2; ++kf)
      #pragma unroll
      for (int p = 0; p < 2; ++p)
        #pragma unroll
        for (int nfc = 0; nfc < 4; ++nfc)
          acc1[p][nfc] = __builtin_amdgcn_mfma_f32_16x16x32_bf16(
              w1p[p][kf], bf[nfc][kf], acc1[p][nfc], 0, 0, 0);

    // bias+relu+pack: C(col=a0col@l15, o=8lg+4p+i) -> layer2 A-frag k=lg*8+j
    bfrag w2t[4];
    #pragma unroll
    for (int nfd = 0; nfd < 4; ++nfd)
      w2t[nfd] = *reinterpret_cast<const bfrag*>(
          W2 + (size_t)(nfd * 16 + l15) * 256 + oc * 32 + lg * 8);

    #pragma unroll
    for (int nfc = 0; nfc < 4; ++nfc) {
      union { unsigned int u[4]; bfrag v; } cv;
      cv.u[0] = cvtpk(fmaxf(acc1[0][nfc][0] + b1q[0].x, 0.f),
                      fmaxf(acc1[0][nfc][1] + b1q[0].y, 0.f));
      cv.u[1] = cvtpk(fmaxf(acc1[0][nfc][2] + b1q[0].z, 0.f),
                      fmaxf(acc1[0][nfc][3] + b1q[0].w, 0.f));
      cv.u[2] = cvtpk(fmaxf(acc1[1][nfc][0] + b1q[1].x, 0.f),
                      fmaxf(acc1[1][nfc][1] + b1q[1].y, 0.f));
      cv.u[3] = cvtpk(fmaxf(acc1[1][nfc][2] + b1q[1].z, 0.f),
                      fmaxf(acc1[1][nfc][3] + b1q[1].w, 0.f));
      #pragma unroll
      for (int nfd = 0; nfd < 4; ++nfd)
        acc2[nfc][nfd] = __builtin_amdgcn_mfma_f32_16x16x32_bf16(
            cv.v, w2t[nfd], acc2[nfc][nfd], 0, 0, 0);
    }
  }

  // epilogue (round-6 verified): bias+scale, softmax over 16 neighbors, PV
  #pragma unroll
  for (int mf = 0; mf < 4; ++mf) {
    float fsel = 0.f;
    #pragma unroll
    for (int nf = 0; nf < 4; ++nf) {
      float b2v = B2[nf * 16 + l15];
      float v[4];
      #pragma unroll
      for (int i = 0; i < 4; ++i) v[i] = (acc2[mf][nf][i] + b2v) * 0.125f;
      float mx = fmaxf(fmaxf(v[0], v[1]), fmaxf(v[2], v[3]));
      mx = fmaxf(mx, __shfl_xor(mx, 16, 64));
      mx = fmaxf(mx, __shfl_xor(mx, 32, 64));
      float e[4], s = 0.f;
      #pragma unroll
      for (int i = 0; i < 4; ++i) { e[i] = exp2f((v[i] - mx) * 1.44269504088896f); s += e[i]; }
      s += __shfl_xor(s, 16, 64);
      s += __shfl_xor(s, 32, 64);
      float inv = 1.f / s;
      float fp = 0.f;
      #pragma unroll
      for (int i = 0; i < 4; ++i) {
        int col = m0 + mf * 16 + lg * 4 + i;
        float vpv = bf2f(vpg[(size_t)col * 64 + nf * 16 + l15]);
        fp = fmaf(e[i] * inv, vpv, fp);
      }
      fp += __shfl_xor(fp, 16, 64);
      fp += __shfl_xor(fp, 32, 64);
      if (lg == nf) fsel = fp;
    }
    int pt = blockIdx.x * 16 + wid * 4 + mf;
    fb[((size_t)up * NPT + pt) * 64 + lane] = f2bf(fsel);
  }
}

// ---------------------------------------------------------------------------
extern "C" void kernel_launch(void* const* d_in, const int* in_sizes, int n_in,
                              void* d_out, int out_size, void* d_ws, size_t ws_size,
                              hipStream_t stream)
{
  const float* fq   = (const float*)d_in[0];
  const float* fk   = (const float*)d_in[1];
  const float* xyz  = (const float*)d_in[2];
  const float* w1   = (const float*)d_in[3];
  const float* b1   = (const float*)d_in[4];
  const float* w2   = (const float*)d_in[5];
  const float* b2   = (const float*)d_in[6];
  const float* wres = (const float*)d_in[7];
  const float* bres = (const float*)d_in[8];
  const float* wq   = (const float*)d_in[9];
  const float* bq   = (const float*)d_in[10];
  const float* wk   = (const float*)d_in[11];
  const float* bk   = (const float*)d_in[12];
  const float* wv   = (const float*)d_in[13];
  const float* bv   = (const float*)d_in[14];
  const float* wp1  = (const float*)d_in[15];
  const float* bp1  = (const float*)d_in[16];
  const float* wp2  = (const float*)d_in[17];
  const float* bp2  = (const float*)d_in[18];
  const float* wa1  = (const float*)d_in[19];
  const float* ba1  = (const float*)d_in[20];
  const float* wa2  = (const float*)d_in[21];
  const float* ba2  = (const float*)d_in[22];
  const float* wo   = (const float*)d_in[23];
  const float* bo   = (const float*)d_in[24];
  const float* wr   = (const float*)d_in[25];
  const float* br   = (const float*)d_in[26];
  float* out = (float*)d_out;
  (void)in_sizes; (void)n_in; (void)out_size; (void)ws_size;

  unsigned short* u    = (unsigned short*)d_ws;
  unsigned short* wreg = u;                        //   839,680
  unsigned short* xqb  = wreg + 839680;            // 4,194,304
  unsigned short* xkb  = xqb  + 4194304;
  unsigned short* ftsb = xkb  + 4194304;
  unsigned short* h1b  = ftsb + 4194304;           // reused as fbb
  unsigned short* a0g  = h1b  + 4194304;           // 16,777,216 (aliases t1)
  unsigned short* vpg  = a0g  + 16777216;          // 16,777,216 (aliases posb)
  unsigned short* qb   = vpg  + 16777216;          // 1,048,576
  unsigned short* kb   = qb   + 1048576;
  unsigned short* vb   = kb   + 1048576;
  int*   ids  = (int*)(vb + 1048576);              // 262,144 ints
  float* bsum = (float*)(ids + 262144);            // 1,472 floats

  unsigned short* w1b   = wreg;
  unsigned short* w2b   = wreg + 131072;
  unsigned short* wresb = wreg + 196608;
  unsigned short* wqb   = wreg + 327680;
  unsigned short* wrb   = wreg + 442368;
  unsigned short* wob   = wreg + 376832;
  unsigned short* wa1b  = wreg + 704512;
  unsigned short* wa2b  = wreg + 770048;
  unsigned short* wp2b  = wreg + 835584;
  unsigned short* t1    = a0g;    // alias: t1 dead before a0g written
  unsigned short* posb  = vpg;    // alias: consumed in place by prep2
  unsigned short* fbb   = h1b;
  const int BIG = 1 << 30;

  dim3 blk(256);

  wcvt_all_k<<<dim3(3286), blk, 0, stream>>>(w1, w2, wres, wq, wk, wv, wo, wr,
                                             wa1, wa2, wp2, bo, br, b2, bres,
                                             bq, bk, bv, wreg, bsum);
  cvtT_k<<<dim3(32, 4, 16), blk, 0, stream>>>(fq, fk, xqb, xkb);
  knn_k<<<dim3(1024), blk, 0, stream>>>(xyz, ids, wp1, bp1, t1);

  // h1 = relu(w1 @ [fq;fk] + b1)  -> bf16 [n][256]
  bgemm_k<0, true, false><<<dim3(128, 4), blk, 0, stream>>>(
      xqb, xkb, xkb, 256, BIG, 256, 256, 256,
      w1b, w1b, BIG, 512, 512, b1, h1b, 512, 256, 0, 0, 0, 0, 0, 0, 0);
  // ftsv = [w2|wres] @ [h1;fq;fk] + (b2+bres) -> bf16 [n][256]
  bgemm_k<0, false, false><<<dim3(128, 4), blk, 0, stream>>>(
      h1b, xqb, xkb, 256, 512, 256, 256, 256,
      w2b, wresb, 256, 256, 512, bsum + 1024, ftsb, 768, 256, 0, 0, 0, 0, 0, 0, 0);
  // q, k, v projections fused: z = 0,1,2 over {xqb,xkb,ftsb} x {wq,wk,wv}
  bgemm_k<0, false, false><<<dim3(128, 1, 3), blk, 0, stream>>>(
      xqb, xqb, xqb, BIG, BIG, 256, 256, 256,
      wqb, wqb, BIG, 256, 256, bsum + 1280, qb, 256, 64, 0,
      4194304, 16384, 16384, 64, 0, 1048576);

  // pos = wp2 @ t1 + bp2  -> bf16 [col][64]   (N = 262144 cols)
  bgemm_k<0, false, false><<<dim3(2048, 1), blk, 0, stream>>>(
      t1, t1, t1, BIG, BIG, 64, 64, 64,
      wp2b, wp2b, BIG, 64, 64, bp2, posb, 64, 64, 0, 0, 0, 0, 0, 0, 0);

  prep2_k<<<dim3(NPT), blk, 0, stream>>>(qb, kb, vb, ids, posb, a0g, vpg);
  attn_mfma_k<<<dim3(1024, UP_), blk, 0, stream>>>(a0g, vpg, wa1b, wa2b, ba1, ba2, fbb);

  // out[:, :, i*2048:(i+1)*2048] = [wo_i|wr_i] @ [f_i; ftsv] + (bo_i+br_i)
  bgemm_k<2, false, true><<<dim3(128, 4, UP_), blk, 0, stream>>>(
      fbb, ftsb, ftsb, 64, BIG, 64, 256, 256,
      wob, wrb, 64, 64, 256,
      bsum, out, 320, 256, 0,
      1048576, 16384, 65536, 256, 2048, 0);
}